// Round 7
// baseline (2235.654 us; speedup 1.0000x reference)
//
#include <hip/hip_runtime.h>

typedef __attribute__((ext_vector_type(8))) short s8v;
typedef __attribute__((ext_vector_type(4))) short s4v;
typedef __attribute__((ext_vector_type(4))) float f4v;
typedef __attribute__((ext_vector_type(4))) unsigned u4v;

#if __has_builtin(__builtin_amdgcn_exp2f)
#define EXP2(x) __builtin_amdgcn_exp2f(x)
#else
#define EXP2(x) exp2f(x)
#endif
#if __has_builtin(__builtin_amdgcn_rcpf)
#define RCP(x) __builtin_amdgcn_rcpf(x)
#else
#define RCP(x) (1.0f/(x))
#endif

#define LOG2E 1.4426950408889634f

__device__ __forceinline__ short f2bf(float f) {
    union { float f; unsigned u; } x; x.f = f;
    unsigned r = (x.u + 0x7FFFu + ((x.u >> 16) & 1u)) >> 16;
    return (short)r;
}
__device__ __forceinline__ float bflo(unsigned u) {
    union { unsigned u; float f; } x; x.u = u << 16; return x.f;
}
__device__ __forceinline__ float bfhi(unsigned u) {
    union { unsigned u; float f; } x; x.u = u & 0xffff0000u; return x.f;
}
__device__ __forceinline__ unsigned cvt_pk_bf16(float lo, float hi) {
    unsigned r;
    asm("v_cvt_pk_bf16_f32 %0, %1, %2" : "=v"(r) : "v"(lo), "v"(hi));
    return r;
}
// LDS-visibility barrier WITHOUT vmcnt drain (keeps prefetch/stores in flight).
__device__ __forceinline__ void lds_barrier() {
    asm volatile("s_waitcnt lgkmcnt(0)\n\ts_barrier" ::: "memory");
}
// agent-scope flag ops (device atomics are cross-XCD coherent; data ordering via __threadfence)
__device__ __forceinline__ void aadd(int* p) {
    __hip_atomic_fetch_add(p, 1, __ATOMIC_RELAXED, __HIP_MEMORY_SCOPE_AGENT);
}
__device__ __forceinline__ void astore(int* p, int v) {
    __hip_atomic_store(p, v, __ATOMIC_RELAXED, __HIP_MEMORY_SCOPE_AGENT);
}
// BOUNDED spin (anti-hang): ~260k iters x s_sleep(8) ~= 25ms max. If sync is
// functional the bound never triggers; if broken, kernel completes with garbage
// -> harness reports absmax instead of a container kill (diagnosable).
__device__ __forceinline__ void wait_ge(const int* p, int v) {
    for (int i = 0; i < (1 << 18); ++i) {
        if (__hip_atomic_load(p, __ATOMIC_ACQUIRE, __HIP_MEMORY_SCOPE_AGENT) >= v) return;
        __builtin_amdgcn_s_sleep(8);
    }
}

// flag indices (ints), zeroed by prep each iteration
#define F_XG   0      // [sb*16 + c] target 2
#define F_L1D  512    // [btile*16 + c] target 2 (both dirs of lstm1 done chunk c)
#define F_YG   768    // [sb*16 + c] target 2
#define F_L1P  1280   // [sb] lstm1 chunks completed (xg buffer-free guard)
#define F_L2P  1312   // [sb] lstm2 chunks completed (yg buffer-free guard)
#define F_TOT  2048

// ---------------- prep (weights->bf16 B-frag, sigmoid pre-scale) + embed MLP + flag zero ----------------
// ROUND-0 PROVEN SHAPE for embed: 256 one-row blocks, 256 threads, ~31KB LDS ->
// ~5 blocks/CU co-residency hides the latency-bound 600-loop.
__global__ __launch_bounds__(256) void prep_embed_kernel(
        const float* __restrict__ k1f, const float* __restrict__ r1f,
        const float* __restrict__ k1b, const float* __restrict__ r1b,
        const float* __restrict__ k2f, const float* __restrict__ r2f,
        const float* __restrict__ k2b, const float* __restrict__ r2b,
        short* __restrict__ WB1, short* __restrict__ WB2,
        const int* __restrict__ inputA, const float* __restrict__ emb,
        const float* __restrict__ w1, const float* __restrict__ b1,
        const float* __restrict__ w2, const float* __restrict__ b2,
        const float* __restrict__ w3, const float* __restrict__ b3,
        float* __restrict__ xe, int* __restrict__ flags) {
    if (blockIdx.x < 1024) {
        if (blockIdx.x == 0) {  // zero sync flags for this iteration
            for (int i = threadIdx.x; i < F_TOT; i += 256) flags[i] = 0;
        }
        int idx = blockIdx.x * 256 + threadIdx.x;
        if (idx < 262144) {  // 2*32*8*64*8
            int j = idx & 7, l = (idx >> 3) & 63, c = (idx >> 9) & 7, n = (idx >> 12) & 31, d = (idx >> 17) & 1;
            int coln = n * 16 + (l & 15);
            int k = c * 32 + ((l >> 4) * 8) + j;
            const float* Wk = d ? k1b : k1f;
            const float* Wr = d ? r1b : r1f;
            float v = (c < 4) ? Wk[k * 512 + coln] : Wr[(k - 128) * 512 + coln];
            float sc = ((n >> 3) == 2) ? 1.0f : -LOG2E;  // gate: 0=i,1=f,2=cc,3=o
            WB1[idx] = f2bf(v * sc);
        }
        if (idx < 163840) {  // 2*16*10*64*8
            int d = idx / 81920, r0 = idx % 81920;
            int n = r0 / 5120, r1 = r0 % 5120;
            int c = r1 / 512, li = r1 % 512;
            int l = li >> 3, j = li & 7;
            int coln = n * 16 + (l & 15);
            int k = c * 32 + ((l >> 4) * 8) + j;
            const float* Wk = d ? k2b : k2f;
            const float* Wr = d ? r2b : r2f;
            float v = (k < 256) ? Wk[k * 256 + coln] : Wr[(k - 256) * 256 + coln];
            float sc = ((n >> 2) == 2) ? 1.0f : -LOG2E;
            WB2[idx] = f2bf(v * sc);
        }
        return;
    }
    __shared__ float row[600];
    __shared__ float h1[256];
    __shared__ float h2[128];
    int b = blockIdx.x - 1024, t = threadIdx.x;
    if (t < 200) {
        int idx = inputA[b * 200 + t];
        row[t * 3 + 0] = emb[idx * 3 + 0];
        row[t * 3 + 1] = emb[idx * 3 + 1];
        row[t * 3 + 2] = emb[idx * 3 + 2];
    }
    __syncthreads();
    float a = b1[t];
    for (int k = 0; k < 600; k++) a += row[k] * w1[k * 256 + t];
    h1[t] = fmaxf(a, 0.f);
    __syncthreads();
    if (t < 128) {
        float a2 = b2[t];
        for (int k = 0; k < 256; k++) a2 += h1[k] * w2[k * 128 + t];
        h2[t] = fmaxf(a2, 0.f);
    }
    __syncthreads();
    if (t < 64) {
        float a3 = b3[t];
        for (int k = 0; k < 128; k++) a3 += h2[k] * w3[k * 64 + t];
        xe[b * 64 + t] = fmaxf(a3, 0.f);
    }
}

// ---------------- persistent megakernel: whole pipeline in ONE launch ----------------
// 192 blocks x 512 thr, 86KB LDS -> 1 block/CU -> all co-resident (192 <= 256 CUs).
// Roles: [0,32) lstm1 | [32,64) lstm2 | [64,128) gemm1 (2/sb) | [128,192) gemm2 (2/sb).
// Chunk-granular flag sync (agent atomics + __threadfence release/acquire, G16).
// Data semantics identical to the proven launch pipeline (incl. forget-gate-tolerated
// early-chunk reads). Recurrence state persists in regs/LDS -> no reload, no fill/drain.
__global__ __launch_bounds__(512, 2) void megakernel(
        const float* __restrict__ x, const short* __restrict__ WB1, const short* __restrict__ WB2,
        const float* __restrict__ bb1f, const float* __restrict__ bb1b,
        const float* __restrict__ bb2f, const float* __restrict__ bb2b,
        short* __restrict__ yfr, short* __restrict__ xgA, short* __restrict__ xgB,
        short* __restrict__ ygA, short* __restrict__ ygB,
        float* __restrict__ h2o, int* __restrict__ flags, int TC, int NC) {
    __shared__ short hA[2048];      // 4KB
    __shared__ short hB[2048];      // 4KB
    __shared__ __align__(16) short stg[38912];    // 76KB (gemm1: 64KB; pad forces 1 block/CU)
    const int tid = threadIdx.x, lane = tid & 63, w = tid >> 6;
    const int bid = blockIdx.x;

    if (bid < 32) {
        // ================= LSTM1 role (persistent, all NC chunks) =================
        const int btile = bid & 15, dir = bid >> 4;
        const int col = lane & 15, q = lane >> 4, u = (w << 4) + col;
        const int sb = dir * 16 + btile;

        s8v wf[4][4];  // h-part chunks 4..7 (loaded ONCE)
#pragma unroll
        for (int ti = 0; ti < 4; ti++)
#pragma unroll
            for (int c = 0; c < 4; c++)
                wf[ti][c] = *(const s8v*)(WB1 + ((((dir * 32 + (w + 8 * ti)) * 8) + 4 + c) * 64 + lane) * 8);

        float cst[4] = {0.f, 0.f, 0.f, 0.f};
        for (int i = tid; i < 2048; i += 512) hA[i] = 0;
        __syncthreads();
        const int hidx = (w >> 1) * 512 + ((u >> 3) & 3) * 128 + (u & 7);

        for (int c = 0; c < NC; ++c) {
            if (tid == 0) wait_ge(&flags[F_XG + sb * 16 + c], 2);
            __syncthreads();
            __threadfence();  // acquire: see gemm1's xg stores (cross-XCD)
            const int t0 = c * TC;
            const short* xgp = ((c & 1) ? xgB : xgA) + (size_t)sb * TC * 8192 + w * 1024 + lane * 8;
            u4v pe0 = *(const u4v*)(xgp);
            u4v pe1 = *(const u4v*)(xgp + 512);
            u4v po0 = *(const u4v*)(xgp + 8192);
            u4v po1 = *(const u4v*)(xgp + 8192 + 512);

            for (int s = 0; s < TC; s += 2) {
                {   // even step: read hA, write hB
                    s8v ah[4];
#pragma unroll
                    for (int cc = 0; cc < 4; cc++) ah[cc] = *(const s8v*)&hA[(cc * 64 + lane) * 8];
                    f4v acc[4];
                    acc[0][0] = bflo(pe0[0]); acc[0][1] = bfhi(pe0[0]); acc[0][2] = bflo(pe0[1]); acc[0][3] = bfhi(pe0[1]);
                    acc[1][0] = bflo(pe0[2]); acc[1][1] = bfhi(pe0[2]); acc[1][2] = bflo(pe0[3]); acc[1][3] = bfhi(pe0[3]);
                    acc[2][0] = bflo(pe1[0]); acc[2][1] = bfhi(pe1[0]); acc[2][2] = bflo(pe1[1]); acc[2][3] = bfhi(pe1[1]);
                    acc[3][0] = bflo(pe1[2]); acc[3][1] = bfhi(pe1[2]); acc[3][2] = bflo(pe1[3]); acc[3][3] = bfhi(pe1[3]);
                    {
                        const short* np = xgp + (size_t)(s + 2) * 8192;
                        pe0 = *(const u4v*)np;
                        pe1 = *(const u4v*)(np + 512);
                    }
#pragma unroll
                    for (int cc = 0; cc < 4; cc++)
#pragma unroll
                        for (int ti = 0; ti < 4; ti++)
                            acc[ti] = __builtin_amdgcn_mfma_f32_16x16x32_bf16(ah[cc], wf[ti][cc], acc[ti], 0, 0, 0);
                    if (w >= 4 && s > 0) {
                        int tp = t0 + s - 1;
                        if (dir) tp = 511 - tp;
                        s8v hv = (w == 4) ? ah[0] : (w == 5) ? ah[1] : (w == 6) ? ah[2] : ah[3];
                        *(s8v*)(yfr + (((size_t)(btile * 512 + tp) * 8) + dir * 4 + (w - 4)) * 512 + lane * 8) = hv;
                    }
                    float hv_[4];
#pragma unroll
                    for (int r = 0; r < 4; r++) {
                        float Ei = EXP2(acc[0][r]);
                        float Ef = EXP2(acc[1][r]);
                        float Eo = EXP2(acc[3][r]);
                        float rv = fmaxf(acc[2][r], 0.f);
                        float di = 1.f + Ei, df = 1.f + Ef;
                        float cn = fmaf(cst[r], di, rv * df) * RCP(di * df);
                        cst[r] = cn;
                        hv_[r] = fmaxf(cn, 0.f) * RCP(1.f + Eo);
                    }
                    unsigned p01 = cvt_pk_bf16(hv_[0], hv_[1]);
                    unsigned p23 = cvt_pk_bf16(hv_[2], hv_[3]);
                    short* hb = &hB[hidx + (q << 5)];
                    hb[0]  = (short)p01;  hb[8]  = (short)(p01 >> 16);
                    hb[16] = (short)p23;  hb[24] = (short)(p23 >> 16);
                    lds_barrier();
                }
                {   // odd step: read hB, write hA
                    s8v ah[4];
#pragma unroll
                    for (int cc = 0; cc < 4; cc++) ah[cc] = *(const s8v*)&hB[(cc * 64 + lane) * 8];
                    f4v acc[4];
                    acc[0][0] = bflo(po0[0]); acc[0][1] = bfhi(po0[0]); acc[0][2] = bflo(po0[1]); acc[0][3] = bfhi(po0[1]);
                    acc[1][0] = bflo(po0[2]); acc[1][1] = bfhi(po0[2]); acc[1][2] = bflo(po0[3]); acc[1][3] = bfhi(po0[3]);
                    acc[2][0] = bflo(po1[0]); acc[2][1] = bfhi(po1[0]); acc[2][2] = bflo(po1[1]); acc[2][3] = bfhi(po1[1]);
                    acc[3][0] = bflo(po1[2]); acc[3][1] = bfhi(po1[2]); acc[3][2] = bflo(po1[3]); acc[3][3] = bfhi(po1[3]);
                    {
                        const short* np = xgp + (size_t)(s + 3) * 8192;
                        po0 = *(const u4v*)np;
                        po1 = *(const u4v*)(np + 512);
                    }
#pragma unroll
                    for (int cc = 0; cc < 4; cc++)
#pragma unroll
                        for (int ti = 0; ti < 4; ti++)
                            acc[ti] = __builtin_amdgcn_mfma_f32_16x16x32_bf16(ah[cc], wf[ti][cc], acc[ti], 0, 0, 0);
                    if (w >= 4) {
                        int tp = t0 + s;
                        if (dir) tp = 511 - tp;
                        s8v hv = (w == 4) ? ah[0] : (w == 5) ? ah[1] : (w == 6) ? ah[2] : ah[3];
                        *(s8v*)(yfr + (((size_t)(btile * 512 + tp) * 8) + dir * 4 + (w - 4)) * 512 + lane * 8) = hv;
                    }
                    float hv_[4];
#pragma unroll
                    for (int r = 0; r < 4; r++) {
                        float Ei = EXP2(acc[0][r]);
                        float Ef = EXP2(acc[1][r]);
                        float Eo = EXP2(acc[3][r]);
                        float rv = fmaxf(acc[2][r], 0.f);
                        float di = 1.f + Ei, df = 1.f + Ef;
                        float cn = fmaf(cst[r], di, rv * df) * RCP(di * df);
                        cst[r] = cn;
                        hv_[r] = fmaxf(cn, 0.f) * RCP(1.f + Eo);
                    }
                    unsigned p01 = cvt_pk_bf16(hv_[0], hv_[1]);
                    unsigned p23 = cvt_pk_bf16(hv_[2], hv_[3]);
                    short* hb = &hA[hidx + (q << 5)];
                    hb[0]  = (short)p01;  hb[8]  = (short)(p01 >> 16);
                    hb[16] = (short)p23;  hb[24] = (short)(p23 >> 16);
                    lds_barrier();
                }
            }
            if (w >= 4) {  // store h(t0+TC-1)
                int tp = t0 + TC - 1;
                if (dir) tp = 511 - tp;
                s8v hv = *(const s8v*)&hA[((w - 4) * 64 + lane) * 8];
                *(s8v*)(yfr + (((size_t)(btile * 512 + tp) * 8) + dir * 4 + (w - 4)) * 512 + lane * 8) = hv;
            }
            __threadfence();  // release: publish yfr rows of chunk c
            __syncthreads();
            if (tid == 0) {
                aadd(&flags[F_L1D + btile * 16 + c]);
                astore(&flags[F_L1P + sb], c + 1);
            }
        }
        return;
    }

    if (bid < 64) {
        // ================= LSTM2 role (persistent; waves 0-3 compute) =================
        const int btile = (bid - 32) & 15, dir = (bid - 32) >> 4;
        const int b0 = btile << 4;
        const int w4 = w & 3;
        const int col = lane & 15, q = lane >> 4, u = (w4 << 4) + col;
        const int sb = dir * 16 + btile;

        s8v wf[4][2];  // h-part chunks 8,9 (loaded ONCE)
#pragma unroll
        for (int ti = 0; ti < 4; ti++)
#pragma unroll
            for (int c = 0; c < 2; c++)
                wf[ti][c] = *(const s8v*)(WB2 + ((((dir * 16 + (w4 + 4 * ti)) * 10) + 8 + c) * 64 + lane) * 8);

        float cst[4] = {0.f, 0.f, 0.f, 0.f}, hl[4] = {0.f, 0.f, 0.f, 0.f};
        for (int i = tid; i < 1024; i += 512) hA[i] = 0;
        __syncthreads();
        const int hidx = (w4 >> 1) * 512 + ((u >> 3) & 3) * 128 + (u & 7);

        for (int c = 0; c < NC; ++c) {
            if (tid == 0) wait_ge(&flags[F_YG + sb * 16 + c], 2);
            __syncthreads();
            __threadfence();  // acquire: see gemm2's yg stores
            const short* ygp = ((c & 1) ? ygB : ygA) + (size_t)sb * TC * 4096 + w4 * 1024 + lane * 8;
            u4v pe0, pe1, po0, po1;
            if (w < 4) {
                pe0 = *(const u4v*)(ygp);
                pe1 = *(const u4v*)(ygp + 512);
                po0 = *(const u4v*)(ygp + 4096);
                po1 = *(const u4v*)(ygp + 4096 + 512);
            }
            for (int s = 0; s < TC; s += 2) {
                if (w < 4) {  // even
                    s8v ah[2];
#pragma unroll
                    for (int cc = 0; cc < 2; cc++) ah[cc] = *(const s8v*)&hA[(cc * 64 + lane) * 8];
                    f4v acc[4];
                    acc[0][0] = bflo(pe0[0]); acc[0][1] = bfhi(pe0[0]); acc[0][2] = bflo(pe0[1]); acc[0][3] = bfhi(pe0[1]);
                    acc[1][0] = bflo(pe0[2]); acc[1][1] = bfhi(pe0[2]); acc[1][2] = bflo(pe0[3]); acc[1][3] = bfhi(pe0[3]);
                    acc[2][0] = bflo(pe1[0]); acc[2][1] = bfhi(pe1[0]); acc[2][2] = bflo(pe1[1]); acc[2][3] = bfhi(pe1[1]);
                    acc[3][0] = bflo(pe1[2]); acc[3][1] = bfhi(pe1[2]); acc[3][2] = bflo(pe1[3]); acc[3][3] = bfhi(pe1[3]);
                    {
                        const short* np = ygp + (size_t)(s + 2) * 4096;
                        pe0 = *(const u4v*)np;
                        pe1 = *(const u4v*)(np + 512);
                    }
#pragma unroll
                    for (int cc = 0; cc < 2; cc++)
#pragma unroll
                        for (int ti = 0; ti < 4; ti++)
                            acc[ti] = __builtin_amdgcn_mfma_f32_16x16x32_bf16(ah[cc], wf[ti][cc], acc[ti], 0, 0, 0);
#pragma unroll
                    for (int r = 0; r < 4; r++) {
                        float Ei = EXP2(acc[0][r]);
                        float Ef = EXP2(acc[1][r]);
                        float Eo = EXP2(acc[3][r]);
                        float rv = fmaxf(acc[2][r], 0.f);
                        float di = 1.f + Ei, df = 1.f + Ef;
                        float cn = fmaf(cst[r], di, rv * df) * RCP(di * df);
                        cst[r] = cn;
                        hl[r] = fmaxf(cn, 0.f) * RCP(1.f + Eo);
                    }
                    unsigned p01 = cvt_pk_bf16(hl[0], hl[1]);
                    unsigned p23 = cvt_pk_bf16(hl[2], hl[3]);
                    short* hb = &hB[hidx + (q << 5)];
                    hb[0]  = (short)p01;  hb[8]  = (short)(p01 >> 16);
                    hb[16] = (short)p23;  hb[24] = (short)(p23 >> 16);
                }
                lds_barrier();
                if (w < 4) {  // odd
                    s8v ah[2];
#pragma unroll
                    for (int cc = 0; cc < 2; cc++) ah[cc] = *(const s8v*)&hB[(cc * 64 + lane) * 8];
                    f4v acc[4];
                    acc[0][0] = bflo(po0[0]); acc[0][1] = bfhi(po0[0]); acc[0][2] = bflo(po0[1]); acc[0][3] = bfhi(po0[1]);
                    acc[1][0] = bflo(po0[2]); acc[1][1] = bfhi(po0[2]); acc[1][2] = bflo(po0[3]); acc[1][3] = bfhi(po0[3]);
                    acc[2][0] = bflo(po1[0]); acc[2][1] = bfhi(po1[0]); acc[2][2] = bflo(po1[1]); acc[2][3] = bfhi(po1[1]);
                    acc[3][0] = bflo(po1[2]); acc[3][1] = bfhi(po1[2]); acc[3][2] = bflo(po1[3]); acc[3][3] = bfhi(po1[3]);
                    {
                        const short* np = ygp + (size_t)(s + 3) * 4096;
                        po0 = *(const u4v*)np;
                        po1 = *(const u4v*)(np + 512);
                    }
#pragma unroll
                    for (int cc = 0; cc < 2; cc++)
#pragma unroll
                        for (int ti = 0; ti < 4; ti++)
                            acc[ti] = __builtin_amdgcn_mfma_f32_16x16x32_bf16(ah[cc], wf[ti][cc], acc[ti], 0, 0, 0);
#pragma unroll
                    for (int r = 0; r < 4; r++) {
                        float Ei = EXP2(acc[0][r]);
                        float Ef = EXP2(acc[1][r]);
                        float Eo = EXP2(acc[3][r]);
                        float rv = fmaxf(acc[2][r], 0.f);
                        float di = 1.f + Ei, df = 1.f + Ef;
                        float cn = fmaf(cst[r], di, rv * df) * RCP(di * df);
                        cst[r] = cn;
                        hl[r] = fmaxf(cn, 0.f) * RCP(1.f + Eo);
                    }
                    unsigned p01 = cvt_pk_bf16(hl[0], hl[1]);
                    unsigned p23 = cvt_pk_bf16(hl[2], hl[3]);
                    short* hb = &hA[hidx + (q << 5)];
                    hb[0]  = (short)p01;  hb[8]  = (short)(p01 >> 16);
                    hb[16] = (short)p23;  hb[24] = (short)(p23 >> 16);
                }
                lds_barrier();
            }
            __syncthreads();
            if (tid == 0) astore(&flags[F_L2P + sb], c + 1);  // yg buffer-free guard only
        }
        if (w < 4) {
#pragma unroll
            for (int r = 0; r < 4; r++)
                h2o[((dir * 256) + b0 + q * 4 + r) * 64 + u] = hl[r];
        }
        return;
    }

    if (bid < 128) {
        // ================= GEMM1 role (persistent, 2 blocks/sb, 16 slices/chunk) =================
        const int g = bid - 64;           // 0..63
        const int sb = g >> 1, half = g & 1;
        const int btile = sb & 15, dir = sb >> 4;
        const int b0 = btile << 4;
        s8v wf[4][4];
#pragma unroll
        for (int ti = 0; ti < 4; ti++)
#pragma unroll
            for (int c = 0; c < 4; c++)
                wf[ti][c] = *(const s8v*)(WB1 + ((((dir * 32 + (w + 8 * ti)) * 8) + c) * 64 + lane) * 8);
        const float* bb = dir ? bb1b : bb1f;
        float bias[4];
#pragma unroll
        for (int ti = 0; ti < 4; ti++) {
            const int tile = w + 8 * ti;
            float sc = ((tile >> 3) == 2) ? 1.0f : -LOG2E;
            bias[ti] = sc * bb[tile * 16 + (lane & 15)];
        }
        const int half2 = lane >> 5;
        const int f0 = (lane & 31) * 4;
        const int cx = f0 >> 5, qq = (f0 >> 3) & 3, j0 = f0 & 7;

        for (int c = 0; c < NC; ++c) {
            if (c >= 2) {  // xg(c) buffer reused from chunk c-2: wait consumer done
                if (tid == 0) wait_ge(&flags[F_L1P + sb], c - 1);
                __syncthreads();
            }
            short* xg_w = (c & 1) ? xgB : xgA;
            const int t0 = c * TC;
            // stage 16 slices (wave w stages slices w and 8+w)
#pragma unroll
            for (int r2 = 0; r2 < 2; r2++) {
                const int si = r2 * 8 + w;
                int tglob = t0 + half * 16 + si;
                if (dir) tglob = 511 - tglob;
#pragma unroll
                for (int rr = 0; rr < 8; rr++) {
                    const int m = rr * 2 + half2;
                    const float* xp = x + ((size_t)(b0 + m) * 512 + tglob) * 128 + f0;
                    f4v v4 = *(const f4v*)xp;
                    const int slot = (qq << 4) | ((m ^ qq ^ (cx << 1)) & 15);
                    s4v pk;
#pragma unroll
                    for (int j = 0; j < 4; j++) pk[j] = f2bf(v4[j]);
                    *(s4v*)&stg[(((si * 4 + cx) * 64 + slot) * 8) + j0] = pk;
                }
            }
            __syncthreads();
#pragma unroll 2
            for (int si = 0; si < 16; si++) {
                s8v a[4];
#pragma unroll
                for (int cc = 0; cc < 4; cc++) {
                    const int slot = lane ^ (lane >> 4) ^ (cc << 1);
                    a[cc] = *(const s8v*)&stg[((si * 4 + cc) * 64 + slot) * 8];
                }
                f4v acc[4];
#pragma unroll
                for (int ti = 0; ti < 4; ti++) { f4v z = {0.f, 0.f, 0.f, 0.f}; acc[ti] = z; }
#pragma unroll
                for (int cc = 0; cc < 4; cc++)
#pragma unroll
                    for (int ti = 0; ti < 4; ti++)
                        acc[ti] = __builtin_amdgcn_mfma_f32_16x16x32_bf16(a[cc], wf[ti][cc], acc[ti], 0, 0, 0);
                const int lt = half * 16 + si;
                short* outp = xg_w + (((size_t)sb * TC + lt) * 8 + w) * 1024 + lane * 8;
#pragma unroll
                for (int p = 0; p < 2; p++) {
                    s8v v;
#pragma unroll
                    for (int j = 0; j < 4; j++) {
                        v[j]     = f2bf(acc[2 * p][j]     + bias[2 * p]);
                        v[4 + j] = f2bf(acc[2 * p + 1][j] + bias[2 * p + 1]);
                    }
                    *(s8v*)(outp + p * 512) = v;
                }
            }
            __threadfence();  // release: publish xg chunk c
            __syncthreads();
            if (tid == 0) aadd(&flags[F_XG + sb * 16 + c]);
        }
        return;
    }

    // ================= GEMM2 role (persistent, 2 blocks/sb, 16 slices/chunk) =================
    {
        const int g = bid - 128;          // 0..63
        const int sb2 = g >> 1, half = g & 1;
        const int btile = sb2 & 15, dir = sb2 >> 4;
        const int w4 = w & 3, wg = w >> 2;
        s8v wf[4][8];
#pragma unroll
        for (int ti = 0; ti < 4; ti++)
#pragma unroll
            for (int c = 0; c < 8; c++)
                wf[ti][c] = *(const s8v*)(WB2 + ((((dir * 16 + (w4 + 4 * ti)) * 10) + c) * 64 + lane) * 8);
        const float* bb = dir ? bb2b : bb2f;
        float bias[4];
#pragma unroll
        for (int ti = 0; ti < 4; ti++) {
            const int tile = w4 + 4 * ti;
            float sc = ((tile >> 2) == 2) ? 1.0f : -LOG2E;
            bias[ti] = sc * bb[tile * 16 + (lane & 15)];
        }
        for (int c = 0; c < NC; ++c) {
            if (tid == 0) {
                wait_ge(&flags[F_L1D + btile * 16 + c], 2);   // lstm1 chunk c done (both dirs)
                if (c >= 2) wait_ge(&flags[F_L2P + sb2], c - 1);  // yg buffer free
            }
            __syncthreads();
            __threadfence();  // acquire: see lstm1's yfr stores
            short* yg_w = (c & 1) ? ygB : ygA;
            const int t0 = c * TC;
#pragma unroll 2
            for (int si = 0; si < 8; si++) {
                const int lt = half * 16 + wg * 8 + si;
                int tglob = t0 + lt;
                if (dir) tglob = 511 - tglob;
                s8v a[8];
#pragma unroll
                for (int cc = 0; cc < 8; cc++)
                    a[cc] = *(const s8v*)(yfr + (((size_t)(btile * 512 + tglob) * 8) + cc) * 512 + lane * 8);
                f4v acc[4];
#pragma unroll
                for (int ti = 0; ti < 4; ti++) { f4v z = {0.f, 0.f, 0.f, 0.f}; acc[ti] = z; }
#pragma unroll
                for (int cc = 0; cc < 8; cc++)
#pragma unroll
                    for (int ti = 0; ti < 4; ti++)
                        acc[ti] = __builtin_amdgcn_mfma_f32_16x16x32_bf16(a[cc], wf[ti][cc], acc[ti], 0, 0, 0);
                short* outp = yg_w + (((size_t)sb2 * TC + lt) * 4 + w4) * 1024 + lane * 8;
#pragma unroll
                for (int p = 0; p < 2; p++) {
                    s8v v;
#pragma unroll
                    for (int j = 0; j < 4; j++) {
                        v[j]     = f2bf(acc[2 * p][j]     + bias[2 * p]);
                        v[4 + j] = f2bf(acc[2 * p + 1][j] + bias[2 * p + 1]);
                    }
                    *(s8v*)(outp + p * 512) = v;
                }
            }
            __threadfence();  // release: publish yg chunk c
            __syncthreads();
            if (tid == 0) aadd(&flags[F_YG + sb2 * 16 + c]);
        }
    }
}

// ---------------- final heads (fp32) ----------------
__global__ void heads_kernel(const float* __restrict__ xe, const float* __restrict__ h2o,
                             const float* __restrict__ wz1, const float* __restrict__ bz1,
                             const float* __restrict__ wz2, const float* __restrict__ bz2,
                             const float* __restrict__ wt1, const float* __restrict__ bt1,
                             const float* __restrict__ wt2, const float* __restrict__ bt2,
                             float* __restrict__ out) {
    int b = threadIdx.x;  // 256 threads, 1 block
    float cz0 = bz1[0], cz1 = bz1[1], ct0 = bt1[0], ct1 = bt1[1];
#pragma unroll 4
    for (int k = 0; k < 192; k++) {
        float v = (k < 64) ? xe[b * 64 + k]
                : (k < 128) ? h2o[b * 64 + (k - 64)]
                            : h2o[(256 + b) * 64 + (k - 128)];
        cz0 += v * wz1[k * 2 + 0];
        cz1 += v * wz1[k * 2 + 1];
        ct0 += v * wt1[k * 2 + 0];
        ct1 += v * wt1[k * 2 + 1];
    }
    cz0 = fmaxf(cz0, 0.f); cz1 = fmaxf(cz1, 0.f);
    ct0 = fmaxf(ct0, 0.f); ct1 = fmaxf(ct1, 0.f);
    out[b] = cz0 * wz2[0] + cz1 * wz2[1] + bz2[0];
    out[256 + b] = ct0 * wt2[0] + ct1 * wt2[1] + bt2[0];
}

extern "C" void kernel_launch(void* const* d_in, const int* in_sizes, int n_in,
                              void* d_out, int out_size, void* d_ws, size_t ws_size,
                              hipStream_t stream) {
    const int*   inputA = (const int*)d_in[0];
    const float* inputB = (const float*)d_in[1];
    const float* emb = (const float*)d_in[2];
    const float* w1  = (const float*)d_in[3];
    const float* b1  = (const float*)d_in[4];
    const float* w2  = (const float*)d_in[5];
    const float* b2  = (const float*)d_in[6];
    const float* w3  = (const float*)d_in[7];
    const float* b3  = (const float*)d_in[8];
    const float* k1f = (const float*)d_in[9];
    const float* r1f = (const float*)d_in[10];
    const float* bb1f= (const float*)d_in[11];
    const float* k1b = (const float*)d_in[12];
    const float* r1b = (const float*)d_in[13];
    const float* bb1b= (const float*)d_in[14];
    const float* k2f = (const float*)d_in[15];
    const float* r2f = (const float*)d_in[16];
    const float* bb2f= (const float*)d_in[17];
    const float* k2b = (const float*)d_in[18];
    const float* r2b = (const float*)d_in[19];
    const float* bb2b= (const float*)d_in[20];
    const float* wz1 = (const float*)d_in[21];
    const float* bz1 = (const float*)d_in[22];
    const float* wz2 = (const float*)d_in[23];
    const float* bz2 = (const float*)d_in[24];
    const float* wt1 = (const float*)d_in[25];
    const float* bt1 = (const float*)d_in[26];
    const float* wt2 = (const float*)d_in[27];
    const float* bt2 = (const float*)d_in[28];

    char* ws = (char*)d_ws;
    short* WB1  = (short*)(ws);                  // 512 KB
    short* WB2  = (short*)(ws + 524288);         // 320 KB
    float* xe   = (float*)(ws + 851968);         // 64 KB
    float* h2o  = (float*)(ws + 917504);         // 128 KB
    int*   flags= (int*)(ws + 1048576);          // 8 KB sync flags
    short* yfr  = (short*)(ws + 2097152);        // 67.1 MB
    float* out  = (float*)d_out;

    const int TC = 32;
    const int NC = 512 / TC;
    short* xgA = (short*)(ws + 69206016);
    short* xgB = xgA + (size_t)TC * 262144;
    short* ygA = xgB + (size_t)TC * 262144;
    short* ygB = ygA + (size_t)TC * 131072;

    prep_embed_kernel<<<1280, 256, 0, stream>>>(k1f, r1f, k1b, r1b, k2f, r2f, k2b, r2b,
                                                WB1, WB2, inputA, emb, w1, b1, w2, b2, w3, b3,
                                                xe, flags);
    // ONE persistent launch: 192 blocks, 86KB LDS -> 1/CU -> all co-resident.
    megakernel<<<192, 512, 0, stream>>>(inputB, WB1, WB2, bb1f, bb1b, bb2f, bb2b,
                                        yfr, xgA, xgB, ygA, ygB, h2o, flags, TC, NC);
    heads_kernel<<<1, 256, 0, stream>>>(xe, h2o, wz1, bz1, wz2, bz2, wt1, bt1, wt2, bt2, out);
}

// Round 8
// 1796.239 us; speedup vs baseline: 1.2446x; 1.2446x over previous
//
#include <hip/hip_runtime.h>

typedef __attribute__((ext_vector_type(8))) short s8v;
typedef __attribute__((ext_vector_type(4))) short s4v;
typedef __attribute__((ext_vector_type(4))) float f4v;
typedef __attribute__((ext_vector_type(4))) unsigned u4v;

#if __has_builtin(__builtin_amdgcn_exp2f)
#define EXP2(x) __builtin_amdgcn_exp2f(x)
#else
#define EXP2(x) exp2f(x)
#endif
#if __has_builtin(__builtin_amdgcn_rcpf)
#define RCP(x) __builtin_amdgcn_rcpf(x)
#else
#define RCP(x) (1.0f/(x))
#endif

#define LOG2E 1.4426950408889634f

__device__ __forceinline__ short f2bf(float f) {
    union { float f; unsigned u; } x; x.f = f;
    unsigned r = (x.u + 0x7FFFu + ((x.u >> 16) & 1u)) >> 16;
    return (short)r;
}
__device__ __forceinline__ float bflo(unsigned u) {
    union { unsigned u; float f; } x; x.u = u << 16; return x.f;
}
__device__ __forceinline__ float bfhi(unsigned u) {
    union { unsigned u; float f; } x; x.u = u & 0xffff0000u; return x.f;
}
__device__ __forceinline__ unsigned cvt_pk_bf16(float lo, float hi) {
    unsigned r;
    asm("v_cvt_pk_bf16_f32 %0, %1, %2" : "=v"(r) : "v"(lo), "v"(hi));
    return r;
}
// LDS-visibility barrier WITHOUT vmcnt drain (keeps prefetch/stores in flight).
__device__ __forceinline__ void lds_barrier() {
    asm volatile("s_waitcnt lgkmcnt(0)\n\ts_barrier" ::: "memory");
}
// agent-scope flag ops (device atomics are cross-XCD coherent; data ordering via __threadfence)
__device__ __forceinline__ void aadd(int* p) {
    __hip_atomic_fetch_add(p, 1, __ATOMIC_RELAXED, __HIP_MEMORY_SCOPE_AGENT);
}
__device__ __forceinline__ void astore(int* p, int v) {
    __hip_atomic_store(p, v, __ATOMIC_RELAXED, __HIP_MEMORY_SCOPE_AGENT);
}
// RELAXED bounded spin. Round-7 post-mortem: ACQUIRE polls emit buffer_inv per
// iteration -> with ~200 spinning blocks that's O(10^3) XCD-wide L2 invalidates/us,
// stalling every working wave's in-order global-mem issue -> uniform 4x stretch
// (2088us measured). Relaxed atomic loads are performed at the agent coherence
// point (bypass L1/L2) so they still OBSERVE producer updates with no invalidate;
// the consumer's single __threadfence() after the wait provides the acquire for
// data. Bound (~12ms) kept as anti-hang diagnostic: if visibility ever failed,
// kernel completes with garbage -> absmax flags it instead of a container kill.
__device__ __forceinline__ void wait_ge(const int* p, int v) {
    for (int i = 0; i < (1 << 14); ++i) {
        if (__hip_atomic_load(p, __ATOMIC_RELAXED, __HIP_MEMORY_SCOPE_AGENT) >= v) return;
        __builtin_amdgcn_s_sleep(16);
    }
}

// flag indices (ints), zeroed by prep each iteration
#define F_XG   0      // [sb*16 + c] target 2
#define F_L1D  512    // [btile*16 + c] target 2 (both dirs of lstm1 done chunk c)
#define F_YG   768    // [sb*16 + c] target 2
#define F_L1P  1280   // [sb] lstm1 chunks completed (xg buffer-free guard)
#define F_L2P  1312   // [sb] lstm2 chunks completed (yg buffer-free guard)
#define F_TOT  2048

// ---------------- prep (weights->bf16 B-frag, sigmoid pre-scale) + embed MLP + flag zero ----------------
// ROUND-0 PROVEN SHAPE for embed: 256 one-row blocks, 256 threads, ~31KB LDS ->
// ~5 blocks/CU co-residency hides the latency-bound 600-loop.
__global__ __launch_bounds__(256) void prep_embed_kernel(
        const float* __restrict__ k1f, const float* __restrict__ r1f,
        const float* __restrict__ k1b, const float* __restrict__ r1b,
        const float* __restrict__ k2f, const float* __restrict__ r2f,
        const float* __restrict__ k2b, const float* __restrict__ r2b,
        short* __restrict__ WB1, short* __restrict__ WB2,
        const int* __restrict__ inputA, const float* __restrict__ emb,
        const float* __restrict__ w1, const float* __restrict__ b1,
        const float* __restrict__ w2, const float* __restrict__ b2,
        const float* __restrict__ w3, const float* __restrict__ b3,
        float* __restrict__ xe, int* __restrict__ flags) {
    if (blockIdx.x < 1024) {
        if (blockIdx.x == 0) {  // zero sync flags for this iteration
            for (int i = threadIdx.x; i < F_TOT; i += 256) flags[i] = 0;
        }
        int idx = blockIdx.x * 256 + threadIdx.x;
        if (idx < 262144) {  // 2*32*8*64*8
            int j = idx & 7, l = (idx >> 3) & 63, c = (idx >> 9) & 7, n = (idx >> 12) & 31, d = (idx >> 17) & 1;
            int coln = n * 16 + (l & 15);
            int k = c * 32 + ((l >> 4) * 8) + j;
            const float* Wk = d ? k1b : k1f;
            const float* Wr = d ? r1b : r1f;
            float v = (c < 4) ? Wk[k * 512 + coln] : Wr[(k - 128) * 512 + coln];
            float sc = ((n >> 3) == 2) ? 1.0f : -LOG2E;  // gate: 0=i,1=f,2=cc,3=o
            WB1[idx] = f2bf(v * sc);
        }
        if (idx < 163840) {  // 2*16*10*64*8
            int d = idx / 81920, r0 = idx % 81920;
            int n = r0 / 5120, r1 = r0 % 5120;
            int c = r1 / 512, li = r1 % 512;
            int l = li >> 3, j = li & 7;
            int coln = n * 16 + (l & 15);
            int k = c * 32 + ((l >> 4) * 8) + j;
            const float* Wk = d ? k2b : k2f;
            const float* Wr = d ? r2b : r2f;
            float v = (k < 256) ? Wk[k * 256 + coln] : Wr[(k - 256) * 256 + coln];
            float sc = ((n >> 2) == 2) ? 1.0f : -LOG2E;
            WB2[idx] = f2bf(v * sc);
        }
        return;
    }
    __shared__ float row[600];
    __shared__ float h1[256];
    __shared__ float h2[128];
    int b = blockIdx.x - 1024, t = threadIdx.x;
    if (t < 200) {
        int idx = inputA[b * 200 + t];
        row[t * 3 + 0] = emb[idx * 3 + 0];
        row[t * 3 + 1] = emb[idx * 3 + 1];
        row[t * 3 + 2] = emb[idx * 3 + 2];
    }
    __syncthreads();
    float a = b1[t];
    for (int k = 0; k < 600; k++) a += row[k] * w1[k * 256 + t];
    h1[t] = fmaxf(a, 0.f);
    __syncthreads();
    if (t < 128) {
        float a2 = b2[t];
        for (int k = 0; k < 256; k++) a2 += h1[k] * w2[k * 128 + t];
        h2[t] = fmaxf(a2, 0.f);
    }
    __syncthreads();
    if (t < 64) {
        float a3 = b3[t];
        for (int k = 0; k < 128; k++) a3 += h2[k] * w3[k * 64 + t];
        xe[b * 64 + t] = fmaxf(a3, 0.f);
    }
}

// ---------------- persistent megakernel: whole pipeline in ONE launch ----------------
// 192 blocks x 512 thr, 86KB LDS -> 1 block/CU -> all co-resident (192 <= 256 CUs).
// Roles: [0,32) lstm1 | [32,64) lstm2 | [64,128) gemm1 (2/sb) | [128,192) gemm2 (2/sb).
// Chunk-granular flag sync (agent atomics + __threadfence release/acquire, G16).
// VERIFIED CORRECT in round 7 (absmax 9.5e-6); this round only fixes the spin cost.
__global__ __launch_bounds__(512, 2) void megakernel(
        const float* __restrict__ x, const short* __restrict__ WB1, const short* __restrict__ WB2,
        const float* __restrict__ bb1f, const float* __restrict__ bb1b,
        const float* __restrict__ bb2f, const float* __restrict__ bb2b,
        short* __restrict__ yfr, short* __restrict__ xgA, short* __restrict__ xgB,
        short* __restrict__ ygA, short* __restrict__ ygB,
        float* __restrict__ h2o, int* __restrict__ flags, int TC, int NC) {
    __shared__ short hA[2048];      // 4KB
    __shared__ short hB[2048];      // 4KB
    __shared__ __align__(16) short stg[38912];    // 76KB (gemm1: 64KB; pad forces 1 block/CU)
    const int tid = threadIdx.x, lane = tid & 63, w = tid >> 6;
    const int bid = blockIdx.x;

    if (bid < 32) {
        // ================= LSTM1 role (persistent, all NC chunks) =================
        const int btile = bid & 15, dir = bid >> 4;
        const int col = lane & 15, q = lane >> 4, u = (w << 4) + col;
        const int sb = dir * 16 + btile;

        s8v wf[4][4];  // h-part chunks 4..7 (loaded ONCE)
#pragma unroll
        for (int ti = 0; ti < 4; ti++)
#pragma unroll
            for (int c = 0; c < 4; c++)
                wf[ti][c] = *(const s8v*)(WB1 + ((((dir * 32 + (w + 8 * ti)) * 8) + 4 + c) * 64 + lane) * 8);

        float cst[4] = {0.f, 0.f, 0.f, 0.f};
        for (int i = tid; i < 2048; i += 512) hA[i] = 0;
        __syncthreads();
        const int hidx = (w >> 1) * 512 + ((u >> 3) & 3) * 128 + (u & 7);

        for (int c = 0; c < NC; ++c) {
            if (tid == 0) wait_ge(&flags[F_XG + sb * 16 + c], 2);
            __syncthreads();
            __threadfence();  // acquire: see gemm1's xg stores (cross-XCD)
            const int t0 = c * TC;
            const short* xgp = ((c & 1) ? xgB : xgA) + (size_t)sb * TC * 8192 + w * 1024 + lane * 8;
            u4v pe0 = *(const u4v*)(xgp);
            u4v pe1 = *(const u4v*)(xgp + 512);
            u4v po0 = *(const u4v*)(xgp + 8192);
            u4v po1 = *(const u4v*)(xgp + 8192 + 512);

            for (int s = 0; s < TC; s += 2) {
                {   // even step: read hA, write hB
                    s8v ah[4];
#pragma unroll
                    for (int cc = 0; cc < 4; cc++) ah[cc] = *(const s8v*)&hA[(cc * 64 + lane) * 8];
                    f4v acc[4];
                    acc[0][0] = bflo(pe0[0]); acc[0][1] = bfhi(pe0[0]); acc[0][2] = bflo(pe0[1]); acc[0][3] = bfhi(pe0[1]);
                    acc[1][0] = bflo(pe0[2]); acc[1][1] = bfhi(pe0[2]); acc[1][2] = bflo(pe0[3]); acc[1][3] = bfhi(pe0[3]);
                    acc[2][0] = bflo(pe1[0]); acc[2][1] = bfhi(pe1[0]); acc[2][2] = bflo(pe1[1]); acc[2][3] = bfhi(pe1[1]);
                    acc[3][0] = bflo(pe1[2]); acc[3][1] = bfhi(pe1[2]); acc[3][2] = bflo(pe1[3]); acc[3][3] = bfhi(pe1[3]);
                    {
                        const short* np = xgp + (size_t)(s + 2) * 8192;
                        pe0 = *(const u4v*)np;
                        pe1 = *(const u4v*)(np + 512);
                    }
#pragma unroll
                    for (int cc = 0; cc < 4; cc++)
#pragma unroll
                        for (int ti = 0; ti < 4; ti++)
                            acc[ti] = __builtin_amdgcn_mfma_f32_16x16x32_bf16(ah[cc], wf[ti][cc], acc[ti], 0, 0, 0);
                    if (w >= 4 && s > 0) {
                        int tp = t0 + s - 1;
                        if (dir) tp = 511 - tp;
                        s8v hv = (w == 4) ? ah[0] : (w == 5) ? ah[1] : (w == 6) ? ah[2] : ah[3];
                        *(s8v*)(yfr + (((size_t)(btile * 512 + tp) * 8) + dir * 4 + (w - 4)) * 512 + lane * 8) = hv;
                    }
                    float hv_[4];
#pragma unroll
                    for (int r = 0; r < 4; r++) {
                        float Ei = EXP2(acc[0][r]);
                        float Ef = EXP2(acc[1][r]);
                        float Eo = EXP2(acc[3][r]);
                        float rv = fmaxf(acc[2][r], 0.f);
                        float di = 1.f + Ei, df = 1.f + Ef;
                        float cn = fmaf(cst[r], di, rv * df) * RCP(di * df);
                        cst[r] = cn;
                        hv_[r] = fmaxf(cn, 0.f) * RCP(1.f + Eo);
                    }
                    unsigned p01 = cvt_pk_bf16(hv_[0], hv_[1]);
                    unsigned p23 = cvt_pk_bf16(hv_[2], hv_[3]);
                    short* hb = &hB[hidx + (q << 5)];
                    hb[0]  = (short)p01;  hb[8]  = (short)(p01 >> 16);
                    hb[16] = (short)p23;  hb[24] = (short)(p23 >> 16);
                    lds_barrier();
                }
                {   // odd step: read hB, write hA
                    s8v ah[4];
#pragma unroll
                    for (int cc = 0; cc < 4; cc++) ah[cc] = *(const s8v*)&hB[(cc * 64 + lane) * 8];
                    f4v acc[4];
                    acc[0][0] = bflo(po0[0]); acc[0][1] = bfhi(po0[0]); acc[0][2] = bflo(po0[1]); acc[0][3] = bfhi(po0[1]);
                    acc[1][0] = bflo(po0[2]); acc[1][1] = bfhi(po0[2]); acc[1][2] = bflo(po0[3]); acc[1][3] = bfhi(po0[3]);
                    acc[2][0] = bflo(po1[0]); acc[2][1] = bfhi(po1[0]); acc[2][2] = bflo(po1[1]); acc[2][3] = bfhi(po1[1]);
                    acc[3][0] = bflo(po1[2]); acc[3][1] = bfhi(po1[2]); acc[3][2] = bflo(po1[3]); acc[3][3] = bfhi(po1[3]);
                    {
                        const short* np = xgp + (size_t)(s + 3) * 8192;
                        po0 = *(const u4v*)np;
                        po1 = *(const u4v*)(np + 512);
                    }
#pragma unroll
                    for (int cc = 0; cc < 4; cc++)
#pragma unroll
                        for (int ti = 0; ti < 4; ti++)
                            acc[ti] = __builtin_amdgcn_mfma_f32_16x16x32_bf16(ah[cc], wf[ti][cc], acc[ti], 0, 0, 0);
                    if (w >= 4) {
                        int tp = t0 + s;
                        if (dir) tp = 511 - tp;
                        s8v hv = (w == 4) ? ah[0] : (w == 5) ? ah[1] : (w == 6) ? ah[2] : ah[3];
                        *(s8v*)(yfr + (((size_t)(btile * 512 + tp) * 8) + dir * 4 + (w - 4)) * 512 + lane * 8) = hv;
                    }
                    float hv_[4];
#pragma unroll
                    for (int r = 0; r < 4; r++) {
                        float Ei = EXP2(acc[0][r]);
                        float Ef = EXP2(acc[1][r]);
                        float Eo = EXP2(acc[3][r]);
                        float rv = fmaxf(acc[2][r], 0.f);
                        float di = 1.f + Ei, df = 1.f + Ef;
                        float cn = fmaf(cst[r], di, rv * df) * RCP(di * df);
                        cst[r] = cn;
                        hv_[r] = fmaxf(cn, 0.f) * RCP(1.f + Eo);
                    }
                    unsigned p01 = cvt_pk_bf16(hv_[0], hv_[1]);
                    unsigned p23 = cvt_pk_bf16(hv_[2], hv_[3]);
                    short* hb = &hA[hidx + (q << 5)];
                    hb[0]  = (short)p01;  hb[8]  = (short)(p01 >> 16);
                    hb[16] = (short)p23;  hb[24] = (short)(p23 >> 16);
                    lds_barrier();
                }
            }
            if (w >= 4) {  // store h(t0+TC-1)
                int tp = t0 + TC - 1;
                if (dir) tp = 511 - tp;
                s8v hv = *(const s8v*)&hA[((w - 4) * 64 + lane) * 8];
                *(s8v*)(yfr + (((size_t)(btile * 512 + tp) * 8) + dir * 4 + (w - 4)) * 512 + lane * 8) = hv;
            }
            __threadfence();  // release: publish yfr rows of chunk c
            __syncthreads();
            if (tid == 0) {
                aadd(&flags[F_L1D + btile * 16 + c]);
                astore(&flags[F_L1P + sb], c + 1);
            }
        }
        return;
    }

    if (bid < 64) {
        // ================= LSTM2 role (persistent; waves 0-3 compute) =================
        const int btile = (bid - 32) & 15, dir = (bid - 32) >> 4;
        const int b0 = btile << 4;
        const int w4 = w & 3;
        const int col = lane & 15, q = lane >> 4, u = (w4 << 4) + col;
        const int sb = dir * 16 + btile;

        s8v wf[4][2];  // h-part chunks 8,9 (loaded ONCE)
#pragma unroll
        for (int ti = 0; ti < 4; ti++)
#pragma unroll
            for (int c = 0; c < 2; c++)
                wf[ti][c] = *(const s8v*)(WB2 + ((((dir * 16 + (w4 + 4 * ti)) * 10) + 8 + c) * 64 + lane) * 8);

        float cst[4] = {0.f, 0.f, 0.f, 0.f}, hl[4] = {0.f, 0.f, 0.f, 0.f};
        for (int i = tid; i < 1024; i += 512) hA[i] = 0;
        __syncthreads();
        const int hidx = (w4 >> 1) * 512 + ((u >> 3) & 3) * 128 + (u & 7);

        for (int c = 0; c < NC; ++c) {
            if (tid == 0) wait_ge(&flags[F_YG + sb * 16 + c], 2);
            __syncthreads();
            __threadfence();  // acquire: see gemm2's yg stores
            const short* ygp = ((c & 1) ? ygB : ygA) + (size_t)sb * TC * 4096 + w4 * 1024 + lane * 8;
            u4v pe0, pe1, po0, po1;
            if (w < 4) {
                pe0 = *(const u4v*)(ygp);
                pe1 = *(const u4v*)(ygp + 512);
                po0 = *(const u4v*)(ygp + 4096);
                po1 = *(const u4v*)(ygp + 4096 + 512);
            }
            for (int s = 0; s < TC; s += 2) {
                if (w < 4) {  // even
                    s8v ah[2];
#pragma unroll
                    for (int cc = 0; cc < 2; cc++) ah[cc] = *(const s8v*)&hA[(cc * 64 + lane) * 8];
                    f4v acc[4];
                    acc[0][0] = bflo(pe0[0]); acc[0][1] = bfhi(pe0[0]); acc[0][2] = bflo(pe0[1]); acc[0][3] = bfhi(pe0[1]);
                    acc[1][0] = bflo(pe0[2]); acc[1][1] = bfhi(pe0[2]); acc[1][2] = bflo(pe0[3]); acc[1][3] = bfhi(pe0[3]);
                    acc[2][0] = bflo(pe1[0]); acc[2][1] = bfhi(pe1[0]); acc[2][2] = bflo(pe1[1]); acc[2][3] = bfhi(pe1[1]);
                    acc[3][0] = bflo(pe1[2]); acc[3][1] = bfhi(pe1[2]); acc[3][2] = bflo(pe1[3]); acc[3][3] = bfhi(pe1[3]);
                    {
                        const short* np = ygp + (size_t)(s + 2) * 4096;
                        pe0 = *(const u4v*)np;
                        pe1 = *(const u4v*)(np + 512);
                    }
#pragma unroll
                    for (int cc = 0; cc < 2; cc++)
#pragma unroll
                        for (int ti = 0; ti < 4; ti++)
                            acc[ti] = __builtin_amdgcn_mfma_f32_16x16x32_bf16(ah[cc], wf[ti][cc], acc[ti], 0, 0, 0);
#pragma unroll
                    for (int r = 0; r < 4; r++) {
                        float Ei = EXP2(acc[0][r]);
                        float Ef = EXP2(acc[1][r]);
                        float Eo = EXP2(acc[3][r]);
                        float rv = fmaxf(acc[2][r], 0.f);
                        float di = 1.f + Ei, df = 1.f + Ef;
                        float cn = fmaf(cst[r], di, rv * df) * RCP(di * df);
                        cst[r] = cn;
                        hl[r] = fmaxf(cn, 0.f) * RCP(1.f + Eo);
                    }
                    unsigned p01 = cvt_pk_bf16(hl[0], hl[1]);
                    unsigned p23 = cvt_pk_bf16(hl[2], hl[3]);
                    short* hb = &hB[hidx + (q << 5)];
                    hb[0]  = (short)p01;  hb[8]  = (short)(p01 >> 16);
                    hb[16] = (short)p23;  hb[24] = (short)(p23 >> 16);
                }
                lds_barrier();
                if (w < 4) {  // odd
                    s8v ah[2];
#pragma unroll
                    for (int cc = 0; cc < 2; cc++) ah[cc] = *(const s8v*)&hB[(cc * 64 + lane) * 8];
                    f4v acc[4];
                    acc[0][0] = bflo(po0[0]); acc[0][1] = bfhi(po0[0]); acc[0][2] = bflo(po0[1]); acc[0][3] = bfhi(po0[1]);
                    acc[1][0] = bflo(po0[2]); acc[1][1] = bfhi(po0[2]); acc[1][2] = bflo(po0[3]); acc[1][3] = bfhi(po0[3]);
                    acc[2][0] = bflo(po1[0]); acc[2][1] = bfhi(po1[0]); acc[2][2] = bflo(po1[1]); acc[2][3] = bfhi(po1[1]);
                    acc[3][0] = bflo(po1[2]); acc[3][1] = bfhi(po1[2]); acc[3][2] = bflo(po1[3]); acc[3][3] = bfhi(po1[3]);
                    {
                        const short* np = ygp + (size_t)(s + 3) * 4096;
                        po0 = *(const u4v*)np;
                        po1 = *(const u4v*)(np + 512);
                    }
#pragma unroll
                    for (int cc = 0; cc < 2; cc++)
#pragma unroll
                        for (int ti = 0; ti < 4; ti++)
                            acc[ti] = __builtin_amdgcn_mfma_f32_16x16x32_bf16(ah[cc], wf[ti][cc], acc[ti], 0, 0, 0);
#pragma unroll
                    for (int r = 0; r < 4; r++) {
                        float Ei = EXP2(acc[0][r]);
                        float Ef = EXP2(acc[1][r]);
                        float Eo = EXP2(acc[3][r]);
                        float rv = fmaxf(acc[2][r], 0.f);
                        float di = 1.f + Ei, df = 1.f + Ef;
                        float cn = fmaf(cst[r], di, rv * df) * RCP(di * df);
                        cst[r] = cn;
                        hl[r] = fmaxf(cn, 0.f) * RCP(1.f + Eo);
                    }
                    unsigned p01 = cvt_pk_bf16(hl[0], hl[1]);
                    unsigned p23 = cvt_pk_bf16(hl[2], hl[3]);
                    short* hb = &hA[hidx + (q << 5)];
                    hb[0]  = (short)p01;  hb[8]  = (short)(p01 >> 16);
                    hb[16] = (short)p23;  hb[24] = (short)(p23 >> 16);
                }
                lds_barrier();
            }
            __syncthreads();
            if (tid == 0) astore(&flags[F_L2P + sb], c + 1);  // yg buffer-free guard only
        }
        if (w < 4) {
#pragma unroll
            for (int r = 0; r < 4; r++)
                h2o[((dir * 256) + b0 + q * 4 + r) * 64 + u] = hl[r];
        }
        return;
    }

    if (bid < 128) {
        // ================= GEMM1 role (persistent, 2 blocks/sb, 16 slices/chunk) =================
        const int g = bid - 64;           // 0..63
        const int sb = g >> 1, half = g & 1;
        const int btile = sb & 15, dir = sb >> 4;
        const int b0 = btile << 4;
        s8v wf[4][4];
#pragma unroll
        for (int ti = 0; ti < 4; ti++)
#pragma unroll
            for (int c = 0; c < 4; c++)
                wf[ti][c] = *(const s8v*)(WB1 + ((((dir * 32 + (w + 8 * ti)) * 8) + c) * 64 + lane) * 8);
        const float* bb = dir ? bb1b : bb1f;
        float bias[4];
#pragma unroll
        for (int ti = 0; ti < 4; ti++) {
            const int tile = w + 8 * ti;
            float sc = ((tile >> 3) == 2) ? 1.0f : -LOG2E;
            bias[ti] = sc * bb[tile * 16 + (lane & 15)];
        }
        const int half2 = lane >> 5;
        const int f0 = (lane & 31) * 4;
        const int cx = f0 >> 5, qq = (f0 >> 3) & 3, j0 = f0 & 7;

        for (int c = 0; c < NC; ++c) {
            if (c >= 2) {  // xg(c) buffer reused from chunk c-2: wait consumer done
                if (tid == 0) wait_ge(&flags[F_L1P + sb], c - 1);
                __syncthreads();
            }
            short* xg_w = (c & 1) ? xgB : xgA;
            const int t0 = c * TC;
            // stage 16 slices (wave w stages slices w and 8+w)
#pragma unroll
            for (int r2 = 0; r2 < 2; r2++) {
                const int si = r2 * 8 + w;
                int tglob = t0 + half * 16 + si;
                if (dir) tglob = 511 - tglob;
#pragma unroll
                for (int rr = 0; rr < 8; rr++) {
                    const int m = rr * 2 + half2;
                    const float* xp = x + ((size_t)(b0 + m) * 512 + tglob) * 128 + f0;
                    f4v v4 = *(const f4v*)xp;
                    const int slot = (qq << 4) | ((m ^ qq ^ (cx << 1)) & 15);
                    s4v pk;
#pragma unroll
                    for (int j = 0; j < 4; j++) pk[j] = f2bf(v4[j]);
                    *(s4v*)&stg[(((si * 4 + cx) * 64 + slot) * 8) + j0] = pk;
                }
            }
            __syncthreads();
#pragma unroll 2
            for (int si = 0; si < 16; si++) {
                s8v a[4];
#pragma unroll
                for (int cc = 0; cc < 4; cc++) {
                    const int slot = lane ^ (lane >> 4) ^ (cc << 1);
                    a[cc] = *(const s8v*)&stg[((si * 4 + cc) * 64 + slot) * 8];
                }
                f4v acc[4];
#pragma unroll
                for (int ti = 0; ti < 4; ti++) { f4v z = {0.f, 0.f, 0.f, 0.f}; acc[ti] = z; }
#pragma unroll
                for (int cc = 0; cc < 4; cc++)
#pragma unroll
                    for (int ti = 0; ti < 4; ti++)
                        acc[ti] = __builtin_amdgcn_mfma_f32_16x16x32_bf16(a[cc], wf[ti][cc], acc[ti], 0, 0, 0);
                const int lt = half * 16 + si;
                short* outp = xg_w + (((size_t)sb * TC + lt) * 8 + w) * 1024 + lane * 8;
#pragma unroll
                for (int p = 0; p < 2; p++) {
                    s8v v;
#pragma unroll
                    for (int j = 0; j < 4; j++) {
                        v[j]     = f2bf(acc[2 * p][j]     + bias[2 * p]);
                        v[4 + j] = f2bf(acc[2 * p + 1][j] + bias[2 * p + 1]);
                    }
                    *(s8v*)(outp + p * 512) = v;
                }
            }
            __threadfence();  // release: publish xg chunk c
            __syncthreads();
            if (tid == 0) aadd(&flags[F_XG + sb * 16 + c]);
        }
        return;
    }

    // ================= GEMM2 role (persistent, 2 blocks/sb, 16 slices/chunk) =================
    {
        const int g = bid - 128;          // 0..63
        const int sb2 = g >> 1, half = g & 1;
        const int btile = sb2 & 15, dir = sb2 >> 4;
        const int w4 = w & 3, wg = w >> 2;
        s8v wf[4][8];
#pragma unroll
        for (int ti = 0; ti < 4; ti++)
#pragma unroll
            for (int c = 0; c < 8; c++)
                wf[ti][c] = *(const s8v*)(WB2 + ((((dir * 16 + (w4 + 4 * ti)) * 10) + c) * 64 + lane) * 8);
        const float* bb = dir ? bb2b : bb2f;
        float bias[4];
#pragma unroll
        for (int ti = 0; ti < 4; ti++) {
            const int tile = w4 + 4 * ti;
            float sc = ((tile >> 2) == 2) ? 1.0f : -LOG2E;
            bias[ti] = sc * bb[tile * 16 + (lane & 15)];
        }
        for (int c = 0; c < NC; ++c) {
            if (tid == 0) {
                wait_ge(&flags[F_L1D + btile * 16 + c], 2);   // lstm1 chunk c done (both dirs)
                if (c >= 2) wait_ge(&flags[F_L2P + sb2], c - 1);  // yg buffer free
            }
            __syncthreads();
            __threadfence();  // acquire: see lstm1's yfr stores
            short* yg_w = (c & 1) ? ygB : ygA;
            const int t0 = c * TC;
#pragma unroll 2
            for (int si = 0; si < 8; si++) {
                const int lt = half * 16 + wg * 8 + si;
                int tglob = t0 + lt;
                if (dir) tglob = 511 - tglob;
                s8v a[8];
#pragma unroll
                for (int cc = 0; cc < 8; cc++)
                    a[cc] = *(const s8v*)(yfr + (((size_t)(btile * 512 + tglob) * 8) + cc) * 512 + lane * 8);
                f4v acc[4];
#pragma unroll
                for (int ti = 0; ti < 4; ti++) { f4v z = {0.f, 0.f, 0.f, 0.f}; acc[ti] = z; }
#pragma unroll
                for (int cc = 0; cc < 8; cc++)
#pragma unroll
                    for (int ti = 0; ti < 4; ti++)
                        acc[ti] = __builtin_amdgcn_mfma_f32_16x16x32_bf16(a[cc], wf[ti][cc], acc[ti], 0, 0, 0);
                short* outp = yg_w + (((size_t)sb2 * TC + lt) * 4 + w4) * 1024 + lane * 8;
#pragma unroll
                for (int p = 0; p < 2; p++) {
                    s8v v;
#pragma unroll
                    for (int j = 0; j < 4; j++) {
                        v[j]     = f2bf(acc[2 * p][j]     + bias[2 * p]);
                        v[4 + j] = f2bf(acc[2 * p + 1][j] + bias[2 * p + 1]);
                    }
                    *(s8v*)(outp + p * 512) = v;
                }
            }
            __threadfence();  // release: publish yg chunk c
            __syncthreads();
            if (tid == 0) aadd(&flags[F_YG + sb2 * 16 + c]);
        }
    }
}

// ---------------- final heads (fp32) ----------------
__global__ void heads_kernel(const float* __restrict__ xe, const float* __restrict__ h2o,
                             const float* __restrict__ wz1, const float* __restrict__ bz1,
                             const float* __restrict__ wz2, const float* __restrict__ bz2,
                             const float* __restrict__ wt1, const float* __restrict__ bt1,
                             const float* __restrict__ wt2, const float* __restrict__ bt2,
                             float* __restrict__ out) {
    int b = threadIdx.x;  // 256 threads, 1 block
    float cz0 = bz1[0], cz1 = bz1[1], ct0 = bt1[0], ct1 = bt1[1];
#pragma unroll 4
    for (int k = 0; k < 192; k++) {
        float v = (k < 64) ? xe[b * 64 + k]
                : (k < 128) ? h2o[b * 64 + (k - 64)]
                            : h2o[(256 + b) * 64 + (k - 128)];
        cz0 += v * wz1[k * 2 + 0];
        cz1 += v * wz1[k * 2 + 1];
        ct0 += v * wt1[k * 2 + 0];
        ct1 += v * wt1[k * 2 + 1];
    }
    cz0 = fmaxf(cz0, 0.f); cz1 = fmaxf(cz1, 0.f);
    ct0 = fmaxf(ct0, 0.f); ct1 = fmaxf(ct1, 0.f);
    out[b] = cz0 * wz2[0] + cz1 * wz2[1] + bz2[0];
    out[256 + b] = ct0 * wt2[0] + ct1 * wt2[1] + bt2[0];
}

extern "C" void kernel_launch(void* const* d_in, const int* in_sizes, int n_in,
                              void* d_out, int out_size, void* d_ws, size_t ws_size,
                              hipStream_t stream) {
    const int*   inputA = (const int*)d_in[0];
    const float* inputB = (const float*)d_in[1];
    const float* emb = (const float*)d_in[2];
    const float* w1  = (const float*)d_in[3];
    const float* b1  = (const float*)d_in[4];
    const float* w2  = (const float*)d_in[5];
    const float* b2  = (const float*)d_in[6];
    const float* w3  = (const float*)d_in[7];
    const float* b3  = (const float*)d_in[8];
    const float* k1f = (const float*)d_in[9];
    const float* r1f = (const float*)d_in[10];
    const float* bb1f= (const float*)d_in[11];
    const float* k1b = (const float*)d_in[12];
    const float* r1b = (const float*)d_in[13];
    const float* bb1b= (const float*)d_in[14];
    const float* k2f = (const float*)d_in[15];
    const float* r2f = (const float*)d_in[16];
    const float* bb2f= (const float*)d_in[17];
    const float* k2b = (const float*)d_in[18];
    const float* r2b = (const float*)d_in[19];
    const float* bb2b= (const float*)d_in[20];
    const float* wz1 = (const float*)d_in[21];
    const float* bz1 = (const float*)d_in[22];
    const float* wz2 = (const float*)d_in[23];
    const float* bz2 = (const float*)d_in[24];
    const float* wt1 = (const float*)d_in[25];
    const float* bt1 = (const float*)d_in[26];
    const float* wt2 = (const float*)d_in[27];
    const float* bt2 = (const float*)d_in[28];

    char* ws = (char*)d_ws;
    short* WB1  = (short*)(ws);                  // 512 KB
    short* WB2  = (short*)(ws + 524288);         // 320 KB
    float* xe   = (float*)(ws + 851968);         // 64 KB
    float* h2o  = (float*)(ws + 917504);         // 128 KB
    int*   flags= (int*)(ws + 1048576);          // 8 KB sync flags
    short* yfr  = (short*)(ws + 2097152);        // 67.1 MB
    float* out  = (float*)d_out;

    const int TC = 32;
    const int NC = 512 / TC;
    short* xgA = (short*)(ws + 69206016);
    short* xgB = xgA + (size_t)TC * 262144;
    short* ygA = xgB + (size_t)TC * 262144;
    short* ygB = ygA + (size_t)TC * 131072;

    prep_embed_kernel<<<1280, 256, 0, stream>>>(k1f, r1f, k1b, r1b, k2f, r2f, k2b, r2b,
                                                WB1, WB2, inputA, emb, w1, b1, w2, b2, w3, b3,
                                                xe, flags);
    // ONE persistent launch: 192 blocks, 86KB LDS -> 1/CU -> all co-resident.
    megakernel<<<192, 512, 0, stream>>>(inputB, WB1, WB2, bb1f, bb1b, bb2f, bb2b,
                                        yfr, xgA, xgB, ygA, ygB, h2o, flags, TC, NC);
    heads_kernel<<<1, 256, 0, stream>>>(xe, h2o, wz1, bz1, wz2, bz2, wt1, bt1, wt2, bt2, out);
}

// Round 9
// 1163.203 us; speedup vs baseline: 1.9220x; 1.5442x over previous
//
#include <hip/hip_runtime.h>

typedef __attribute__((ext_vector_type(8))) short s8v;
typedef __attribute__((ext_vector_type(4))) short s4v;
typedef __attribute__((ext_vector_type(4))) float f4v;
typedef __attribute__((ext_vector_type(4))) unsigned u4v;

#if __has_builtin(__builtin_amdgcn_exp2f)
#define EXP2(x) __builtin_amdgcn_exp2f(x)
#else
#define EXP2(x) exp2f(x)
#endif
#if __has_builtin(__builtin_amdgcn_rcpf)
#define RCP(x) __builtin_amdgcn_rcpf(x)
#else
#define RCP(x) (1.0f/(x))
#endif

#define LOG2E 1.4426950408889634f

__device__ __forceinline__ short f2bf(float f) {
    union { float f; unsigned u; } x; x.f = f;
    unsigned r = (x.u + 0x7FFFu + ((x.u >> 16) & 1u)) >> 16;
    return (short)r;
}
__device__ __forceinline__ float bflo(unsigned u) {
    union { unsigned u; float f; } x; x.u = u << 16; return x.f;
}
__device__ __forceinline__ float bfhi(unsigned u) {
    union { unsigned u; float f; } x; x.u = u & 0xffff0000u; return x.f;
}
__device__ __forceinline__ unsigned cvt_pk_bf16(float lo, float hi) {
    unsigned r;
    asm("v_cvt_pk_bf16_f32 %0, %1, %2" : "=v"(r) : "v"(lo), "v"(hi));
    return r;
}
// LDS-visibility barrier WITHOUT vmcnt drain (keeps prefetch/stores in flight).
__device__ __forceinline__ void lds_barrier() {
    asm volatile("s_waitcnt lgkmcnt(0)\n\ts_barrier" ::: "memory");
}
// ---- agent-scope (sc1) coherent data path: the round-8 post-mortem ----
// Per-chunk __threadfence() = buffer_wbl2 (whole-L2 writeback) x ~2500 over the
// run = the 3x dilation (round 7: 2088us, round 8: 1650us, both fenced).
// Fix: communicated data (yfr/xg/yg) moves via agent-scope RELAXED atomic dword
// loads/stores -> global_load/store_dword sc1: write-through/bypass the
// non-cross-coherent L2, visible at the coherence point -- the same path the
// flags (proven correct r7/r8) already use. Release = each wave's own
// vmcnt(0) drain (emitted by __syncthreads) before the flag-add; acquire =
// flag observe (sc1 loads can't hit stale L2). ZERO wbl2 / buffer_inv.
__device__ __forceinline__ unsigned ald(const unsigned* p) {
    return __hip_atomic_load(p, __ATOMIC_RELAXED, __HIP_MEMORY_SCOPE_AGENT);
}
__device__ __forceinline__ void astd(unsigned* p, unsigned v) {
    __hip_atomic_store(p, v, __ATOMIC_RELAXED, __HIP_MEMORY_SCOPE_AGENT);
}
__device__ __forceinline__ u4v ald4(const void* p) {
    const unsigned* q = (const unsigned*)p;
    u4v r; r[0] = ald(q); r[1] = ald(q + 1); r[2] = ald(q + 2); r[3] = ald(q + 3);
    return r;
}
__device__ __forceinline__ void ast4(void* p, u4v v) {
    unsigned* q = (unsigned*)p;
    astd(q, v[0]); astd(q + 1, v[1]); astd(q + 2, v[2]); astd(q + 3, v[3]);
}
__device__ __forceinline__ u4v s2u(s8v v) { union { s8v s; u4v u; } x; x.s = v; return x.u; }
__device__ __forceinline__ s8v u2s(u4v v) { union { s8v s; u4v u; } x; x.u = v; return x.s; }
// drain own stores to the coherence point before publishing a flag
__device__ __forceinline__ void drain_stores() {
    asm volatile("s_waitcnt vmcnt(0)" ::: "memory");
}
// flag ops (agent atomics, relaxed)
__device__ __forceinline__ void aadd(int* p) {
    __hip_atomic_fetch_add(p, 1, __ATOMIC_RELAXED, __HIP_MEMORY_SCOPE_AGENT);
}
__device__ __forceinline__ void astore(int* p, int v) {
    __hip_atomic_store(p, v, __ATOMIC_RELAXED, __HIP_MEMORY_SCOPE_AGENT);
}
// RELAXED bounded spin (r8). Bound ~7ms kept as anti-hang diagnostic.
__device__ __forceinline__ void wait_ge(const int* p, int v) {
    for (int i = 0; i < (1 << 14); ++i) {
        if (__hip_atomic_load(p, __ATOMIC_RELAXED, __HIP_MEMORY_SCOPE_AGENT) >= v) return;
        __builtin_amdgcn_s_sleep(16);
    }
}

// flag indices (ints), zeroed by prep each iteration
#define F_XG   0      // [sb*16 + c] target 2
#define F_L1D  512    // [btile*16 + c] target 2 (both dirs of lstm1 done chunk c)
#define F_YG   768    // [sb*16 + c] target 2
#define F_L1P  1280   // [sb] lstm1 chunks completed (xg buffer-free guard)
#define F_L2P  1312   // [sb] lstm2 chunks completed (yg buffer-free guard)
#define F_TOT  2048

// ---------------- prep (weights->bf16 B-frag, sigmoid pre-scale) + embed MLP + flag zero ----------------
__global__ __launch_bounds__(256) void prep_embed_kernel(
        const float* __restrict__ k1f, const float* __restrict__ r1f,
        const float* __restrict__ k1b, const float* __restrict__ r1b,
        const float* __restrict__ k2f, const float* __restrict__ r2f,
        const float* __restrict__ k2b, const float* __restrict__ r2b,
        short* __restrict__ WB1, short* __restrict__ WB2,
        const int* __restrict__ inputA, const float* __restrict__ emb,
        const float* __restrict__ w1, const float* __restrict__ b1,
        const float* __restrict__ w2, const float* __restrict__ b2,
        const float* __restrict__ w3, const float* __restrict__ b3,
        float* __restrict__ xe, int* __restrict__ flags) {
    if (blockIdx.x < 1024) {
        if (blockIdx.x == 0) {  // zero sync flags for this iteration
            for (int i = threadIdx.x; i < F_TOT; i += 256) flags[i] = 0;
        }
        int idx = blockIdx.x * 256 + threadIdx.x;
        if (idx < 262144) {  // 2*32*8*64*8
            int j = idx & 7, l = (idx >> 3) & 63, c = (idx >> 9) & 7, n = (idx >> 12) & 31, d = (idx >> 17) & 1;
            int coln = n * 16 + (l & 15);
            int k = c * 32 + ((l >> 4) * 8) + j;
            const float* Wk = d ? k1b : k1f;
            const float* Wr = d ? r1b : r1f;
            float v = (c < 4) ? Wk[k * 512 + coln] : Wr[(k - 128) * 512 + coln];
            float sc = ((n >> 3) == 2) ? 1.0f : -LOG2E;  // gate: 0=i,1=f,2=cc,3=o
            WB1[idx] = f2bf(v * sc);
        }
        if (idx < 163840) {  // 2*16*10*64*8
            int d = idx / 81920, r0 = idx % 81920;
            int n = r0 / 5120, r1 = r0 % 5120;
            int c = r1 / 512, li = r1 % 512;
            int l = li >> 3, j = li & 7;
            int coln = n * 16 + (l & 15);
            int k = c * 32 + ((l >> 4) * 8) + j;
            const float* Wk = d ? k2b : k2f;
            const float* Wr = d ? r2b : r2f;
            float v = (k < 256) ? Wk[k * 256 + coln] : Wr[(k - 256) * 256 + coln];
            float sc = ((n >> 2) == 2) ? 1.0f : -LOG2E;
            WB2[idx] = f2bf(v * sc);
        }
        return;
    }
    __shared__ float row[600];
    __shared__ float h1[256];
    __shared__ float h2[128];
    int b = blockIdx.x - 1024, t = threadIdx.x;
    if (t < 200) {
        int idx = inputA[b * 200 + t];
        row[t * 3 + 0] = emb[idx * 3 + 0];
        row[t * 3 + 1] = emb[idx * 3 + 1];
        row[t * 3 + 2] = emb[idx * 3 + 2];
    }
    __syncthreads();
    float a = b1[t];
    for (int k = 0; k < 600; k++) a += row[k] * w1[k * 256 + t];
    h1[t] = fmaxf(a, 0.f);
    __syncthreads();
    if (t < 128) {
        float a2 = b2[t];
        for (int k = 0; k < 256; k++) a2 += h1[k] * w2[k * 128 + t];
        h2[t] = fmaxf(a2, 0.f);
    }
    __syncthreads();
    if (t < 64) {
        float a3 = b3[t];
        for (int k = 0; k < 128; k++) a3 += h2[k] * w3[k * 64 + t];
        xe[b * 64 + t] = fmaxf(a3, 0.f);
    }
}

// ---------------- persistent megakernel: whole pipeline in ONE launch ----------------
// 192 blocks x 512 thr, 86KB LDS -> 1 block/CU -> all co-resident. Roles:
// [0,32) lstm1 | [32,64) lstm2 | [64,128) gemm1 (2/sb) | [128,192) gemm2 (2/sb).
// Flag protocol VERIFIED CORRECT r7/r8 (absmax 9.5e-6). This round: sc1 data
// path + zero fences (see helper comment).
__global__ __launch_bounds__(512, 2) void megakernel(
        const float* __restrict__ x, const short* __restrict__ WB1, const short* __restrict__ WB2,
        const float* __restrict__ bb1f, const float* __restrict__ bb1b,
        const float* __restrict__ bb2f, const float* __restrict__ bb2b,
        short* __restrict__ yfr, short* __restrict__ xgA, short* __restrict__ xgB,
        short* __restrict__ ygA, short* __restrict__ ygB,
        float* __restrict__ h2o, int* __restrict__ flags, int TC, int NC) {
    __shared__ short hA[2048];      // 4KB
    __shared__ short hB[2048];      // 4KB
    __shared__ __align__(16) short stg[38912];    // 76KB (gemm1: 64KB; pad forces 1 block/CU)
    const int tid = threadIdx.x, lane = tid & 63, w = tid >> 6;
    const int bid = blockIdx.x;

    if (bid < 32) {
        // ================= LSTM1 role (persistent, all NC chunks) =================
        const int btile = bid & 15, dir = bid >> 4;
        const int col = lane & 15, q = lane >> 4, u = (w << 4) + col;
        const int sb = dir * 16 + btile;

        s8v wf[4][4];  // h-part chunks 4..7 (loaded ONCE)
#pragma unroll
        for (int ti = 0; ti < 4; ti++)
#pragma unroll
            for (int c = 0; c < 4; c++)
                wf[ti][c] = *(const s8v*)(WB1 + ((((dir * 32 + (w + 8 * ti)) * 8) + 4 + c) * 64 + lane) * 8);

        float cst[4] = {0.f, 0.f, 0.f, 0.f};
        for (int i = tid; i < 2048; i += 512) hA[i] = 0;
        __syncthreads();
        const int hidx = (w >> 1) * 512 + ((u >> 3) & 3) * 128 + (u & 7);

        for (int c = 0; c < NC; ++c) {
            if (tid == 0) wait_ge(&flags[F_XG + sb * 16 + c], 2);
            __syncthreads();   // all data loads below are sc1 -> no fence needed
            const int t0 = c * TC;
            const short* xgp = ((c & 1) ? xgB : xgA) + (size_t)sb * TC * 8192 + w * 1024 + lane * 8;
            u4v pe0 = ald4(xgp);
            u4v pe1 = ald4(xgp + 512);
            u4v po0 = ald4(xgp + 8192);
            u4v po1 = ald4(xgp + 8192 + 512);

            for (int s = 0; s < TC; s += 2) {
                {   // even step: read hA, write hB
                    s8v ah[4];
#pragma unroll
                    for (int cc = 0; cc < 4; cc++) ah[cc] = *(const s8v*)&hA[(cc * 64 + lane) * 8];
                    f4v acc[4];
                    acc[0][0] = bflo(pe0[0]); acc[0][1] = bfhi(pe0[0]); acc[0][2] = bflo(pe0[1]); acc[0][3] = bfhi(pe0[1]);
                    acc[1][0] = bflo(pe0[2]); acc[1][1] = bfhi(pe0[2]); acc[1][2] = bflo(pe0[3]); acc[1][3] = bfhi(pe0[3]);
                    acc[2][0] = bflo(pe1[0]); acc[2][1] = bfhi(pe1[0]); acc[2][2] = bflo(pe1[1]); acc[2][3] = bfhi(pe1[1]);
                    acc[3][0] = bflo(pe1[2]); acc[3][1] = bfhi(pe1[2]); acc[3][2] = bflo(pe1[3]); acc[3][3] = bfhi(pe1[3]);
                    {
                        const short* np = xgp + (size_t)(s + 2) * 8192;
                        pe0 = ald4(np);
                        pe1 = ald4(np + 512);
                    }
#pragma unroll
                    for (int cc = 0; cc < 4; cc++)
#pragma unroll
                        for (int ti = 0; ti < 4; ti++)
                            acc[ti] = __builtin_amdgcn_mfma_f32_16x16x32_bf16(ah[cc], wf[ti][cc], acc[ti], 0, 0, 0);
                    if (w >= 4 && s > 0) {
                        int tp = t0 + s - 1;
                        if (dir) tp = 511 - tp;
                        s8v hv = (w == 4) ? ah[0] : (w == 5) ? ah[1] : (w == 6) ? ah[2] : ah[3];
                        ast4(yfr + (((size_t)(btile * 512 + tp) * 8) + dir * 4 + (w - 4)) * 512 + lane * 8, s2u(hv));
                    }
                    float hv_[4];
#pragma unroll
                    for (int r = 0; r < 4; r++) {
                        float Ei = EXP2(acc[0][r]);
                        float Ef = EXP2(acc[1][r]);
                        float Eo = EXP2(acc[3][r]);
                        float rv = fmaxf(acc[2][r], 0.f);
                        float di = 1.f + Ei, df = 1.f + Ef;
                        float cn = fmaf(cst[r], di, rv * df) * RCP(di * df);
                        cst[r] = cn;
                        hv_[r] = fmaxf(cn, 0.f) * RCP(1.f + Eo);
                    }
                    unsigned p01 = cvt_pk_bf16(hv_[0], hv_[1]);
                    unsigned p23 = cvt_pk_bf16(hv_[2], hv_[3]);
                    short* hb = &hB[hidx + (q << 5)];
                    hb[0]  = (short)p01;  hb[8]  = (short)(p01 >> 16);
                    hb[16] = (short)p23;  hb[24] = (short)(p23 >> 16);
                    lds_barrier();
                }
                {   // odd step: read hB, write hA
                    s8v ah[4];
#pragma unroll
                    for (int cc = 0; cc < 4; cc++) ah[cc] = *(const s8v*)&hB[(cc * 64 + lane) * 8];
                    f4v acc[4];
                    acc[0][0] = bflo(po0[0]); acc[0][1] = bfhi(po0[0]); acc[0][2] = bflo(po0[1]); acc[0][3] = bfhi(po0[1]);
                    acc[1][0] = bflo(po0[2]); acc[1][1] = bfhi(po0[2]); acc[1][2] = bflo(po0[3]); acc[1][3] = bfhi(po0[3]);
                    acc[2][0] = bflo(po1[0]); acc[2][1] = bfhi(po1[0]); acc[2][2] = bflo(po1[1]); acc[2][3] = bfhi(po1[1]);
                    acc[3][0] = bflo(po1[2]); acc[3][1] = bfhi(po1[2]); acc[3][2] = bflo(po1[3]); acc[3][3] = bfhi(po1[3]);
                    {
                        const short* np = xgp + (size_t)(s + 3) * 8192;
                        po0 = ald4(np);
                        po1 = ald4(np + 512);
                    }
#pragma unroll
                    for (int cc = 0; cc < 4; cc++)
#pragma unroll
                        for (int ti = 0; ti < 4; ti++)
                            acc[ti] = __builtin_amdgcn_mfma_f32_16x16x32_bf16(ah[cc], wf[ti][cc], acc[ti], 0, 0, 0);
                    if (w >= 4) {
                        int tp = t0 + s;
                        if (dir) tp = 511 - tp;
                        s8v hv = (w == 4) ? ah[0] : (w == 5) ? ah[1] : (w == 6) ? ah[2] : ah[3];
                        ast4(yfr + (((size_t)(btile * 512 + tp) * 8) + dir * 4 + (w - 4)) * 512 + lane * 8, s2u(hv));
                    }
                    float hv_[4];
#pragma unroll
                    for (int r = 0; r < 4; r++) {
                        float Ei = EXP2(acc[0][r]);
                        float Ef = EXP2(acc[1][r]);
                        float Eo = EXP2(acc[3][r]);
                        float rv = fmaxf(acc[2][r], 0.f);
                        float di = 1.f + Ei, df = 1.f + Ef;
                        float cn = fmaf(cst[r], di, rv * df) * RCP(di * df);
                        cst[r] = cn;
                        hv_[r] = fmaxf(cn, 0.f) * RCP(1.f + Eo);
                    }
                    unsigned p01 = cvt_pk_bf16(hv_[0], hv_[1]);
                    unsigned p23 = cvt_pk_bf16(hv_[2], hv_[3]);
                    short* hb = &hA[hidx + (q << 5)];
                    hb[0]  = (short)p01;  hb[8]  = (short)(p01 >> 16);
                    hb[16] = (short)p23;  hb[24] = (short)(p23 >> 16);
                    lds_barrier();
                }
            }
            if (w >= 4) {  // store h(t0+TC-1)
                int tp = t0 + TC - 1;
                if (dir) tp = 511 - tp;
                s8v hv = *(const s8v*)&hA[((w - 4) * 64 + lane) * 8];
                ast4(yfr + (((size_t)(btile * 512 + tp) * 8) + dir * 4 + (w - 4)) * 512 + lane * 8, s2u(hv));
            }
            drain_stores();     // own sc1 stores reach coherence point
            __syncthreads();    // all waves drained before flag publish
            if (tid == 0) {
                aadd(&flags[F_L1D + btile * 16 + c]);
                astore(&flags[F_L1P + sb], c + 1);
            }
        }
        return;
    }

    if (bid < 64) {
        // ================= LSTM2 role (persistent; waves 0-3 compute) =================
        const int btile = (bid - 32) & 15, dir = (bid - 32) >> 4;
        const int b0 = btile << 4;
        const int w4 = w & 3;
        const int col = lane & 15, q = lane >> 4, u = (w4 << 4) + col;
        const int sb = dir * 16 + btile;

        s8v wf[4][2];  // h-part chunks 8,9 (loaded ONCE)
#pragma unroll
        for (int ti = 0; ti < 4; ti++)
#pragma unroll
            for (int c = 0; c < 2; c++)
                wf[ti][c] = *(const s8v*)(WB2 + ((((dir * 16 + (w4 + 4 * ti)) * 10) + 8 + c) * 64 + lane) * 8);

        float cst[4] = {0.f, 0.f, 0.f, 0.f}, hl[4] = {0.f, 0.f, 0.f, 0.f};
        for (int i = tid; i < 1024; i += 512) hA[i] = 0;
        __syncthreads();
        const int hidx = (w4 >> 1) * 512 + ((u >> 3) & 3) * 128 + (u & 7);

        for (int c = 0; c < NC; ++c) {
            if (tid == 0) wait_ge(&flags[F_YG + sb * 16 + c], 2);
            __syncthreads();   // yg loads below are sc1 -> no fence
            const short* ygp = ((c & 1) ? ygB : ygA) + (size_t)sb * TC * 4096 + w4 * 1024 + lane * 8;
            u4v pe0, pe1, po0, po1;
            if (w < 4) {
                pe0 = ald4(ygp);
                pe1 = ald4(ygp + 512);
                po0 = ald4(ygp + 4096);
                po1 = ald4(ygp + 4096 + 512);
            }
            for (int s = 0; s < TC; s += 2) {
                if (w < 4) {  // even
                    s8v ah[2];
#pragma unroll
                    for (int cc = 0; cc < 2; cc++) ah[cc] = *(const s8v*)&hA[(cc * 64 + lane) * 8];
                    f4v acc[4];
                    acc[0][0] = bflo(pe0[0]); acc[0][1] = bfhi(pe0[0]); acc[0][2] = bflo(pe0[1]); acc[0][3] = bfhi(pe0[1]);
                    acc[1][0] = bflo(pe0[2]); acc[1][1] = bfhi(pe0[2]); acc[1][2] = bflo(pe0[3]); acc[1][3] = bfhi(pe0[3]);
                    acc[2][0] = bflo(pe1[0]); acc[2][1] = bfhi(pe1[0]); acc[2][2] = bflo(pe1[1]); acc[2][3] = bfhi(pe1[1]);
                    acc[3][0] = bflo(pe1[2]); acc[3][1] = bfhi(pe1[2]); acc[3][2] = bflo(pe1[3]); acc[3][3] = bfhi(pe1[3]);
                    {
                        const short* np = ygp + (size_t)(s + 2) * 4096;
                        pe0 = ald4(np);
                        pe1 = ald4(np + 512);
                    }
#pragma unroll
                    for (int cc = 0; cc < 2; cc++)
#pragma unroll
                        for (int ti = 0; ti < 4; ti++)
                            acc[ti] = __builtin_amdgcn_mfma_f32_16x16x32_bf16(ah[cc], wf[ti][cc], acc[ti], 0, 0, 0);
#pragma unroll
                    for (int r = 0; r < 4; r++) {
                        float Ei = EXP2(acc[0][r]);
                        float Ef = EXP2(acc[1][r]);
                        float Eo = EXP2(acc[3][r]);
                        float rv = fmaxf(acc[2][r], 0.f);
                        float di = 1.f + Ei, df = 1.f + Ef;
                        float cn = fmaf(cst[r], di, rv * df) * RCP(di * df);
                        cst[r] = cn;
                        hl[r] = fmaxf(cn, 0.f) * RCP(1.f + Eo);
                    }
                    unsigned p01 = cvt_pk_bf16(hl[0], hl[1]);
                    unsigned p23 = cvt_pk_bf16(hl[2], hl[3]);
                    short* hb = &hB[hidx + (q << 5)];
                    hb[0]  = (short)p01;  hb[8]  = (short)(p01 >> 16);
                    hb[16] = (short)p23;  hb[24] = (short)(p23 >> 16);
                }
                lds_barrier();
                if (w < 4) {  // odd
                    s8v ah[2];
#pragma unroll
                    for (int cc = 0; cc < 2; cc++) ah[cc] = *(const s8v*)&hB[(cc * 64 + lane) * 8];
                    f4v acc[4];
                    acc[0][0] = bflo(po0[0]); acc[0][1] = bfhi(po0[0]); acc[0][2] = bflo(po0[1]); acc[0][3] = bfhi(po0[1]);
                    acc[1][0] = bflo(po0[2]); acc[1][1] = bfhi(po0[2]); acc[1][2] = bflo(po0[3]); acc[1][3] = bfhi(po0[3]);
                    acc[2][0] = bflo(po1[0]); acc[2][1] = bfhi(po1[0]); acc[2][2] = bflo(po1[1]); acc[2][3] = bfhi(po1[1]);
                    acc[3][0] = bflo(po1[2]); acc[3][1] = bfhi(po1[2]); acc[3][2] = bflo(po1[3]); acc[3][3] = bfhi(po1[3]);
                    {
                        const short* np = ygp + (size_t)(s + 3) * 4096;
                        po0 = ald4(np);
                        po1 = ald4(np + 512);
                    }
#pragma unroll
                    for (int cc = 0; cc < 2; cc++)
#pragma unroll
                        for (int ti = 0; ti < 4; ti++)
                            acc[ti] = __builtin_amdgcn_mfma_f32_16x16x32_bf16(ah[cc], wf[ti][cc], acc[ti], 0, 0, 0);
#pragma unroll
                    for (int r = 0; r < 4; r++) {
                        float Ei = EXP2(acc[0][r]);
                        float Ef = EXP2(acc[1][r]);
                        float Eo = EXP2(acc[3][r]);
                        float rv = fmaxf(acc[2][r], 0.f);
                        float di = 1.f + Ei, df = 1.f + Ef;
                        float cn = fmaf(cst[r], di, rv * df) * RCP(di * df);
                        cst[r] = cn;
                        hl[r] = fmaxf(cn, 0.f) * RCP(1.f + Eo);
                    }
                    unsigned p01 = cvt_pk_bf16(hl[0], hl[1]);
                    unsigned p23 = cvt_pk_bf16(hl[2], hl[3]);
                    short* hb = &hA[hidx + (q << 5)];
                    hb[0]  = (short)p01;  hb[8]  = (short)(p01 >> 16);
                    hb[16] = (short)p23;  hb[24] = (short)(p23 >> 16);
                }
                lds_barrier();
            }
            __syncthreads();
            if (tid == 0) astore(&flags[F_L2P + sb], c + 1);  // yg buffer-free guard only
        }
        if (w < 4) {
#pragma unroll
            for (int r = 0; r < 4; r++)
                h2o[((dir * 256) + b0 + q * 4 + r) * 64 + u] = hl[r];
        }
        return;
    }

    if (bid < 128) {
        // ================= GEMM1 role (persistent, 2 blocks/sb, 16 slices/chunk) =================
        const int g = bid - 64;           // 0..63
        const int sb = g >> 1, half = g & 1;
        const int btile = sb & 15, dir = sb >> 4;
        const int b0 = btile << 4;
        s8v wf[4][4];
#pragma unroll
        for (int ti = 0; ti < 4; ti++)
#pragma unroll
            for (int c = 0; c < 4; c++)
                wf[ti][c] = *(const s8v*)(WB1 + ((((dir * 32 + (w + 8 * ti)) * 8) + c) * 64 + lane) * 8);
        const float* bb = dir ? bb1b : bb1f;
        float bias[4];
#pragma unroll
        for (int ti = 0; ti < 4; ti++) {
            const int tile = w + 8 * ti;
            float sc = ((tile >> 3) == 2) ? 1.0f : -LOG2E;
            bias[ti] = sc * bb[tile * 16 + (lane & 15)];
        }
        const int half2 = lane >> 5;
        const int f0 = (lane & 31) * 4;
        const int cx = f0 >> 5, qq = (f0 >> 3) & 3, j0 = f0 & 7;

        for (int c = 0; c < NC; ++c) {
            if (c >= 2) {  // xg(c) buffer reused from chunk c-2: wait consumer done
                if (tid == 0) wait_ge(&flags[F_L1P + sb], c - 1);
                __syncthreads();
            }
            short* xg_w = (c & 1) ? xgB : xgA;
            const int t0 = c * TC;
            // stage 16 slices (wave w stages slices w and 8+w)
#pragma unroll
            for (int r2 = 0; r2 < 2; r2++) {
                const int si = r2 * 8 + w;
                int tglob = t0 + half * 16 + si;
                if (dir) tglob = 511 - tglob;
#pragma unroll
                for (int rr = 0; rr < 8; rr++) {
                    const int m = rr * 2 + half2;
                    const float* xp = x + ((size_t)(b0 + m) * 512 + tglob) * 128 + f0;
                    f4v v4 = *(const f4v*)xp;
                    const int slot = (qq << 4) | ((m ^ qq ^ (cx << 1)) & 15);
                    s4v pk;
#pragma unroll
                    for (int j = 0; j < 4; j++) pk[j] = f2bf(v4[j]);
                    *(s4v*)&stg[(((si * 4 + cx) * 64 + slot) * 8) + j0] = pk;
                }
            }
            __syncthreads();
#pragma unroll 2
            for (int si = 0; si < 16; si++) {
                s8v a[4];
#pragma unroll
                for (int cc = 0; cc < 4; cc++) {
                    const int slot = lane ^ (lane >> 4) ^ (cc << 1);
                    a[cc] = *(const s8v*)&stg[((si * 4 + cc) * 64 + slot) * 8];
                }
                f4v acc[4];
#pragma unroll
                for (int ti = 0; ti < 4; ti++) { f4v z = {0.f, 0.f, 0.f, 0.f}; acc[ti] = z; }
#pragma unroll
                for (int cc = 0; cc < 4; cc++)
#pragma unroll
                    for (int ti = 0; ti < 4; ti++)
                        acc[ti] = __builtin_amdgcn_mfma_f32_16x16x32_bf16(a[cc], wf[ti][cc], acc[ti], 0, 0, 0);
                const int lt = half * 16 + si;
                short* outp = xg_w + (((size_t)sb * TC + lt) * 8 + w) * 1024 + lane * 8;
#pragma unroll
                for (int p = 0; p < 2; p++) {
                    s8v v;
#pragma unroll
                    for (int j = 0; j < 4; j++) {
                        v[j]     = f2bf(acc[2 * p][j]     + bias[2 * p]);
                        v[4 + j] = f2bf(acc[2 * p + 1][j] + bias[2 * p + 1]);
                    }
                    ast4(outp + p * 512, s2u(v));
                }
            }
            drain_stores();
            __syncthreads();
            if (tid == 0) aadd(&flags[F_XG + sb * 16 + c]);
        }
        return;
    }

    // ================= GEMM2 role (persistent, 2 blocks/sb, 16 slices/chunk) =================
    {
        const int g = bid - 128;          // 0..63
        const int sb2 = g >> 1, half = g & 1;
        const int btile = sb2 & 15, dir = sb2 >> 4;
        const int w4 = w & 3, wg = w >> 2;
        s8v wf[4][8];
#pragma unroll
        for (int ti = 0; ti < 4; ti++)
#pragma unroll
            for (int c = 0; c < 8; c++)
                wf[ti][c] = *(const s8v*)(WB2 + ((((dir * 16 + (w4 + 4 * ti)) * 10) + c) * 64 + lane) * 8);
        const float* bb = dir ? bb2b : bb2f;
        float bias[4];
#pragma unroll
        for (int ti = 0; ti < 4; ti++) {
            const int tile = w4 + 4 * ti;
            float sc = ((tile >> 2) == 2) ? 1.0f : -LOG2E;
            bias[ti] = sc * bb[tile * 16 + (lane & 15)];
        }
        for (int c = 0; c < NC; ++c) {
            if (tid == 0) {
                wait_ge(&flags[F_L1D + btile * 16 + c], 2);   // lstm1 chunk c done (both dirs)
                if (c >= 2) wait_ge(&flags[F_L2P + sb2], c - 1);  // yg buffer free
            }
            __syncthreads();   // yfr loads below are sc1 -> no fence
            short* yg_w = (c & 1) ? ygB : ygA;
            const int t0 = c * TC;
#pragma unroll 2
            for (int si = 0; si < 8; si++) {
                const int lt = half * 16 + wg * 8 + si;
                int tglob = t0 + lt;
                if (dir) tglob = 511 - tglob;
                s8v a[8];
#pragma unroll
                for (int cc = 0; cc < 8; cc++)
                    a[cc] = u2s(ald4(yfr + (((size_t)(btile * 512 + tglob) * 8) + cc) * 512 + lane * 8));
                f4v acc[4];
#pragma unroll
                for (int ti = 0; ti < 4; ti++) { f4v z = {0.f, 0.f, 0.f, 0.f}; acc[ti] = z; }
#pragma unroll
                for (int cc = 0; cc < 8; cc++)
#pragma unroll
                    for (int ti = 0; ti < 4; ti++)
                        acc[ti] = __builtin_amdgcn_mfma_f32_16x16x32_bf16(a[cc], wf[ti][cc], acc[ti], 0, 0, 0);
                short* outp = yg_w + (((size_t)sb2 * TC + lt) * 4 + w4) * 1024 + lane * 8;
#pragma unroll
                for (int p = 0; p < 2; p++) {
                    s8v v;
#pragma unroll
                    for (int j = 0; j < 4; j++) {
                        v[j]     = f2bf(acc[2 * p][j]     + bias[2 * p]);
                        v[4 + j] = f2bf(acc[2 * p + 1][j] + bias[2 * p + 1]);
                    }
                    ast4(outp + p * 512, s2u(v));
                }
            }
            drain_stores();
            __syncthreads();
            if (tid == 0) aadd(&flags[F_YG + sb2 * 16 + c]);
        }
    }
}

// ---------------- final heads (fp32) ----------------
__global__ void heads_kernel(const float* __restrict__ xe, const float* __restrict__ h2o,
                             const float* __restrict__ wz1, const float* __restrict__ bz1,
                             const float* __restrict__ wz2, const float* __restrict__ bz2,
                             const float* __restrict__ wt1, const float* __restrict__ bt1,
                             const float* __restrict__ wt2, const float* __restrict__ bt2,
                             float* __restrict__ out) {
    int b = threadIdx.x;  // 256 threads, 1 block
    float cz0 = bz1[0], cz1 = bz1[1], ct0 = bt1[0], ct1 = bt1[1];
#pragma unroll 4
    for (int k = 0; k < 192; k++) {
        float v = (k < 64) ? xe[b * 64 + k]
                : (k < 128) ? h2o[b * 64 + (k - 64)]
                            : h2o[(256 + b) * 64 + (k - 128)];
        cz0 += v * wz1[k * 2 + 0];
        cz1 += v * wz1[k * 2 + 1];
        ct0 += v * wt1[k * 2 + 0];
        ct1 += v * wt1[k * 2 + 1];
    }
    cz0 = fmaxf(cz0, 0.f); cz1 = fmaxf(cz1, 0.f);
    ct0 = fmaxf(ct0, 0.f); ct1 = fmaxf(ct1, 0.f);
    out[b] = cz0 * wz2[0] + cz1 * wz2[1] + bz2[0];
    out[256 + b] = ct0 * wt2[0] + ct1 * wt2[1] + bt2[0];
}

extern "C" void kernel_launch(void* const* d_in, const int* in_sizes, int n_in,
                              void* d_out, int out_size, void* d_ws, size_t ws_size,
                              hipStream_t stream) {
    const int*   inputA = (const int*)d_in[0];
    const float* inputB = (const float*)d_in[1];
    const float* emb = (const float*)d_in[2];
    const float* w1  = (const float*)d_in[3];
    const float* b1  = (const float*)d_in[4];
    const float* w2  = (const float*)d_in[5];
    const float* b2  = (const float*)d_in[6];
    const float* w3  = (const float*)d_in[7];
    const float* b3  = (const float*)d_in[8];
    const float* k1f = (const float*)d_in[9];
    const float* r1f = (const float*)d_in[10];
    const float* bb1f= (const float*)d_in[11];
    const float* k1b = (const float*)d_in[12];
    const float* r1b = (const float*)d_in[13];
    const float* bb1b= (const float*)d_in[14];
    const float* k2f = (const float*)d_in[15];
    const float* r2f = (const float*)d_in[16];
    const float* bb2f= (const float*)d_in[17];
    const float* k2b = (const float*)d_in[18];
    const float* r2b = (const float*)d_in[19];
    const float* bb2b= (const float*)d_in[20];
    const float* wz1 = (const float*)d_in[21];
    const float* bz1 = (const float*)d_in[22];
    const float* wz2 = (const float*)d_in[23];
    const float* bz2 = (const float*)d_in[24];
    const float* wt1 = (const float*)d_in[25];
    const float* bt1 = (const float*)d_in[26];
    const float* wt2 = (const float*)d_in[27];
    const float* bt2 = (const float*)d_in[28];

    char* ws = (char*)d_ws;
    short* WB1  = (short*)(ws);                  // 512 KB
    short* WB2  = (short*)(ws + 524288);         // 320 KB
    float* xe   = (float*)(ws + 851968);         // 64 KB
    float* h2o  = (float*)(ws + 917504);         // 128 KB
    int*   flags= (int*)(ws + 1048576);          // 8 KB sync flags
    short* yfr  = (short*)(ws + 2097152);        // 67.1 MB
    float* out  = (float*)d_out;

    const int TC = 32;
    const int NC = 512 / TC;
    short* xgA = (short*)(ws + 69206016);
    short* xgB = xgA + (size_t)TC * 262144;
    short* ygA = xgB + (size_t)TC * 262144;
    short* ygB = ygA + (size_t)TC * 131072;

    prep_embed_kernel<<<1280, 256, 0, stream>>>(k1f, r1f, k1b, r1b, k2f, r2f, k2b, r2b,
                                                WB1, WB2, inputA, emb, w1, b1, w2, b2, w3, b3,
                                                xe, flags);
    // ONE persistent launch: 192 blocks, 86KB LDS -> 1/CU -> all co-resident.
    megakernel<<<192, 512, 0, stream>>>(inputB, WB1, WB2, bb1f, bb1b, bb2f, bb2b,
                                        yfr, xgA, xgB, ygA, ygB, h2o, flags, TC, NC);
    heads_kernel<<<1, 256, 0, stream>>>(xe, h2o, wz1, bz1, wz2, bz2, wt1, bt1, wt2, bt2, out);
}